// Round 2
// baseline (1424.947 us; speedup 1.0000x reference)
//
#include <hip/hip_runtime.h>

#define NN   8192
#define FEAT 192
#define HID  256
#define NCLS 1000
#define KNN  9
#define NPP  512          // nodes per image (8192 / 16)
#define NIMG 16
#define KSPL 384          // split-bf16 K (hi|lo concatenated)
#define FINF 3.402823466e38f

typedef unsigned short ushort_t;
typedef __attribute__((ext_vector_type(8))) __bf16 bf16x8;
typedef __attribute__((ext_vector_type(4))) float f32x4;

#define ASYNC16(gptr, lptr)                                                  \
  __builtin_amdgcn_global_load_lds(                                          \
      (const __attribute__((address_space(1))) void*)(gptr),                 \
      (__attribute__((address_space(3))) void*)(lptr), 16, 0, 0)

// ---------------------------------------------------------------------------
__device__ __forceinline__ ushort_t f2bf_rne(float f) {
  unsigned u = __float_as_uint(f);
  u += 0x7FFF + ((u >> 16) & 1);          // round-to-nearest-even
  return (ushort_t)(u >> 16);
}

// sorted-ascending top-9 insertion; strict '<' keeps earlier entry on ties.
__device__ __forceinline__ void topk_insert(float (&tv)[KNN], int (&tc)[KNN],
                                            float v, int c) {
  if (v < tv[KNN - 1]) {
    tv[KNN - 1] = v; tc[KNN - 1] = c;
#pragma unroll
    for (int p = KNN - 1; p > 0; --p) {
      if (tv[p] < tv[p - 1]) {
        float fv = tv[p]; tv[p] = tv[p - 1]; tv[p - 1] = fv;
        int   fi = tc[p]; tc[p] = tc[p - 1]; tc[p - 1] = fi;
      }
    }
  }
}

// ---------------------------------------------------------------------------
__global__ __launch_bounds__(256) void k_norms(const float* __restrict__ x,
                                               float* __restrict__ sq) {
  int wid  = (blockIdx.x * 256 + threadIdx.x) >> 6;
  int lane = threadIdx.x & 63;
  if (wid >= NN) return;
  const float* row = x + (size_t)wid * FEAT;
  float s = 0.f;
  for (int f = lane; f < FEAT; f += 64) { float v = row[f]; s += v * v; }
#pragma unroll
  for (int off = 32; off > 0; off >>= 1) s += __shfl_down(s, off);
  if (lane == 0) sq[wid] = s;
}

// ---------------------------------------------------------------------------
// split-bf16: xs[i][0..191] = bf16(x), xs[i][192..383] = bf16(x - hi)
__global__ __launch_bounds__(256) void k_split(const float* __restrict__ x,
                                               ushort_t* __restrict__ xs) {
  int i = blockIdx.x * 256 + threadIdx.x;
  if (i >= NN * FEAT) return;
  int r = i / FEAT, c = i - r * FEAT;
  float v = x[i];
  ushort_t h = f2bf_rne(v);
  float hf = __uint_as_float((unsigned)h << 16);
  ushort_t l = f2bf_rne(v - hf);
  xs[(size_t)r * KSPL + c]        = h;
  xs[(size_t)r * KSPL + FEAT + c] = l;
}

// ---------------------------------------------------------------------------
// MFMA distance + per-colblock top-9. 128x128 tile, K=384 bf16 (hi|lo split).
// Staging: global_load_lds width-16, granule-XOR swizzle (cuts ds_read_b128
// conflicts 8-way -> 4-way). 4 waves, each 64x64 via 4x4 grid of 16x16x32.
// Epilogue: per-wave 64x17 LDS chunks -> top-9; LDS total 26624 B (was 74 KB).
__global__ __launch_bounds__(256) void k_dist_topk(
    const ushort_t* __restrict__ xs, const float* __restrict__ sq,
    float* __restrict__ cand_v, ushort_t* __restrict__ cand_i) {
  __shared__ __align__(16) char smem[26624];
  ushort_t* As = (ushort_t*)smem;            // [128][32] (granule-swizzled)
  ushort_t* Bs = (ushort_t*)(smem + 8192);
  float*    Es = (float*)smem;               // wave w at +w*1088: [64][17]
  float*    Ms = (float*)(smem + 17408);     // [128][18] merge buf

  const int t    = threadIdx.x;
  const int lane = t & 63;
  const int w    = t >> 6;
  const int l15  = lane & 15, lq = lane >> 4;
  const int rowStart = blockIdx.y * 128;
  const int colStart = blockIdx.x * 128;
  const int mrow = (w >> 1) * 64;            // wave's row quadrant
  const int ncol = (w & 1) * 64;             // wave's col quadrant

  // staging geometry: chunk m = (w*2+q)*64 + lane; r = m>>2, granule = m&3,
  // swizzled global granule gs = g ^ (r&3); LDS stays linearly packed.
  const int m0 = w * 128 + lane;             // q=0 chunk; q=1 is m0+64
  const int r0 = m0 >> 2, r1 = r0 + 16;
  const int g0 = m0 & 3;
  const int gs0 = g0 ^ (r0 & 3);
  const int gs1 = g0 ^ (r1 & 3);
  const ushort_t* gA0 = xs + (size_t)(rowStart + r0) * KSPL + gs0 * 8;
  const ushort_t* gA1 = xs + (size_t)(rowStart + r1) * KSPL + gs1 * 8;
  const ushort_t* gB0 = xs + (size_t)(colStart + r0) * KSPL + gs0 * 8;
  const ushort_t* gB1 = xs + (size_t)(colStart + r1) * KSPL + gs1 * 8;
  ushort_t* lA = As + w * 1024;              // + q*512 elements
  ushort_t* lB = Bs + w * 1024;

  // fragment LDS offsets (swizzle-aware): phys granule = lq ^ (l15&3)
  const int pg = (lq ^ (l15 & 3)) * 8;
  int aoff[4], boff[4];
#pragma unroll
  for (int ti = 0; ti < 4; ++ti) aoff[ti] = (mrow + ti * 16 + l15) * 32 + pg;
#pragma unroll
  for (int tj = 0; tj < 4; ++tj) boff[tj] = (ncol + tj * 16 + l15) * 32 + pg;

  f32x4 acc[4][4] = {};

  for (int kt = 0; kt < 12; ++kt) {
    const int k0 = kt * 32;
    ASYNC16(gA0 + k0, lA);
    ASYNC16(gA1 + k0, lA + 512);
    ASYNC16(gB0 + k0, lB);
    ASYNC16(gB1 + k0, lB + 512);
    __syncthreads();                         // drains vmcnt: tile visible
    bf16x8 af[4], bf[4];
#pragma unroll
    for (int ti = 0; ti < 4; ++ti) af[ti] = *(const bf16x8*)(As + aoff[ti]);
#pragma unroll
    for (int tj = 0; tj < 4; ++tj) bf[tj] = *(const bf16x8*)(Bs + boff[tj]);
#pragma unroll
    for (int ti = 0; ti < 4; ++ti)
#pragma unroll
      for (int tj = 0; tj < 4; ++tj)
        acc[ti][tj] = __builtin_amdgcn_mfma_f32_16x16x32_bf16(
            af[ti], bf[tj], acc[ti][tj], 0, 0, 0);
    __syncthreads();                         // all reads done before re-stage
  }

  // ---- epilogue: v = sq[j] - 2*dot, per-row top-9 over this block's cols
  float sqc[4];
#pragma unroll
  for (int tj = 0; tj < 4; ++tj)
    sqc[tj] = sq[colStart + ncol + tj * 16 + l15];

  float tv[KNN]; int tc[KNN];
#pragma unroll
  for (int n = 0; n < KNN; ++n) { tv[n] = FINF; tc[n] = -1; }

  float* Ew = Es + w * 1088;                 // this wave's [64][17] scratch
  for (int tj = 0; tj < 4; ++tj) {
    __syncthreads();
#pragma unroll
    for (int ti = 0; ti < 4; ++ti)
#pragma unroll
      for (int p = 0; p < 4; ++p)
        Ew[(ti * 16 + lq * 4 + p) * 17 + l15] = sqc[tj] - 2.0f * acc[ti][tj][p];
    __syncthreads();
    int cbase = colStart + ncol + tj * 16;
#pragma unroll
    for (int c = 0; c < 16; ++c)
      topk_insert(tv, tc, Ew[lane * 17 + c], cbase + c);
  }

  // merge the two waves sharing each row half, write candidates
  __syncthreads();
  if (w & 1) {
#pragma unroll
    for (int n = 0; n < KNN; ++n) {
      Ms[(mrow + lane) * 18 + n]     = tv[n];
      Ms[(mrow + lane) * 18 + 9 + n] = __int_as_float(tc[n]);
    }
  }
  __syncthreads();
  if (!(w & 1)) {
#pragma unroll
    for (int n = 0; n < KNN; ++n)
      topk_insert(tv, tc, Ms[(mrow + lane) * 18 + n],
                  __float_as_int(Ms[(mrow + lane) * 18 + 9 + n]));
    size_t base = (((size_t)(rowStart + mrow + lane)) * 64 + blockIdx.x) * KNN;
#pragma unroll
    for (int n = 0; n < KNN; ++n) {
      cand_v[base + n] = tv[n];
      cand_i[base + n] = (ushort_t)tc[n];
    }
  }
}

// ---------------------------------------------------------------------------
// one wave per row: merge 64 colblocks x 9 = 576 candidates -> final 9 idx
__global__ __launch_bounds__(256) void k_reduce_topk(
    const float* __restrict__ cand_v, const ushort_t* __restrict__ cand_i,
    int* __restrict__ idx) {
  int wid  = (blockIdx.x * 256 + threadIdx.x) >> 6;
  int lane = threadIdx.x & 63;
  if (wid >= NN) return;
  const float*    cv = cand_v + (size_t)wid * 576;
  const ushort_t* ci = cand_i + (size_t)wid * 576;
  float tv[KNN]; int tc[KNN];
#pragma unroll
  for (int n = 0; n < KNN; ++n) { tv[n] = FINF; tc[n] = -1; }
#pragma unroll
  for (int m = 0; m < KNN; ++m)
    topk_insert(tv, tc, cv[lane + 64 * m], (int)ci[lane + 64 * m]);

  for (int r = 0; r < KNN; ++r) {
    float bv = tv[0]; int bc = tc[0];
#pragma unroll
    for (int n = 1; n < KNN; ++n)
      if (tv[n] < bv) { bv = tv[n]; bc = tc[n]; }
#pragma unroll
    for (int off = 32; off > 0; off >>= 1) {
      float ov = __shfl_xor(bv, off);
      int   oc = __shfl_xor(bc, off);
      if (ov < bv || (ov == bv && oc < bc)) { bv = ov; bc = oc; }
    }
#pragma unroll
    for (int n = 0; n < KNN; ++n)
      if (tc[n] == bc) tv[n] = FINF;
    if (lane == 0) idx[wid * KNN + r] = bc;
  }
}

// ---------------------------------------------------------------------------
__global__ __launch_bounds__(256) void k_gather(
    const float* __restrict__ h, const int* __restrict__ idx,
    float* __restrict__ agg, int C) {
  int wid  = (blockIdx.x * 256 + threadIdx.x) >> 6;
  int lane = threadIdx.x & 63;
  if (wid >= NN) return;
  int nb[KNN];
#pragma unroll
  for (int n = 0; n < KNN; ++n) nb[n] = idx[wid * KNN + n];
  for (int f = lane; f < C; f += 64) {
    float s = 0.f;
#pragma unroll
    for (int n = 0; n < KNN; ++n) s += h[(size_t)nb[n] * C + f];
    agg[(size_t)wid * C + f] = s * (1.0f / KNN);
  }
}

// ---------------------------------------------------------------------------
__global__ void k_zero(float* __restrict__ out, int n) {
  int i = blockIdx.x * 256 + threadIdx.x;
  if (i < n) out[i] = 0.f;
}

// ---------------------------------------------------------------------------
// h = relu([A1|A2] @ [W1;W2] + bias); POOL: fused global mean pool (atomic)
template <int BM, int BN, int TM, int TN, bool POOL>
__global__ __launch_bounds__(256) void k_sage_gemm(
    const float* __restrict__ A1, const float* __restrict__ A2, int K1, int K2,
    const float* __restrict__ W1, const float* __restrict__ W2,
    const float* __restrict__ bias, float* __restrict__ out, int N) {
  constexpr int BK = 8;
  __shared__ float As[BK][BM];
  __shared__ float Bs[BK][BN];
  __shared__ float red[POOL ? (BM / TM) * BN : 1];

  const int t  = threadIdx.x;
  const int tx = t & 15, ty = t >> 4;
  const int rowStart = blockIdx.y * BM;
  const int colStart = blockIdx.x * BN;

  const int  alr = t >> 1, alk = (t & 1) * 4;
  const bool aact = t < BM * 2;
  constexpr int BW = BN / 4;
  const int  bkr = t / BW, bnc = (t % BW) * 4;
  const bool bact = t < BK * BW;

  float acc[TM][TN] = {};
  const int KT = K1 + K2;

  for (int k0 = 0; k0 < KT; k0 += BK) {
    float4 av = {0, 0, 0, 0}, bv = {0, 0, 0, 0};
    if (aact) {
      int kk = k0 + alk;
      const float* src = (kk < K1)
          ? A1 + (size_t)(rowStart + alr) * K1 + kk
          : A2 + (size_t)(rowStart + alr) * K2 + (kk - K1);
      av = *(const float4*)src;
    }
    if (bact) {
      int kk = k0 + bkr;
      const float* wsrc = (kk < K1) ? W1 + (size_t)kk * N
                                    : W2 + (size_t)(kk - K1) * N;
      int col = colStart + bnc;
      if (col < N) bv = *(const float4*)(wsrc + col);
    }
    __syncthreads();
    if (aact) {
      As[alk + 0][alr] = av.x; As[alk + 1][alr] = av.y;
      As[alk + 2][alr] = av.z; As[alk + 3][alr] = av.w;
    }
    if (bact) *(float4*)&Bs[bkr][bnc] = bv;
    __syncthreads();
#pragma unroll
    for (int k = 0; k < BK; ++k) {
      float a[TM], b[TN];
#pragma unroll
      for (int i = 0; i < TM; i += 4)
        *(float4*)&a[i] = *(const float4*)&As[k][ty * TM + i];
#pragma unroll
      for (int j = 0; j < TN; j += 4)
        *(float4*)&b[j] = *(const float4*)&Bs[k][tx * TN + j];
#pragma unroll
      for (int i = 0; i < TM; ++i)
#pragma unroll
        for (int j = 0; j < TN; ++j)
          acc[i][j] = fmaf(a[i], b[j], acc[i][j]);
    }
  }

  float bvals[TN];
#pragma unroll
  for (int j = 0; j < TN; ++j) {
    int col = colStart + tx * TN + j;
    bvals[j] = (col < N) ? bias[col] : 0.f;
  }

  if (!POOL) {
#pragma unroll
    for (int i = 0; i < TM; ++i) {
      int row = rowStart + ty * TM + i;
#pragma unroll
      for (int j = 0; j < TN; ++j) {
        int col = colStart + tx * TN + j;
        if (col < N)
          out[(size_t)row * N + col] = fmaxf(acc[i][j] + bvals[j], 0.f);
      }
    }
  } else {
    float srow[TN];
#pragma unroll
    for (int j = 0; j < TN; ++j) {
      float s = 0.f;
#pragma unroll
      for (int i = 0; i < TM; ++i) s += fmaxf(acc[i][j] + bvals[j], 0.f);
      srow[j] = s;
    }
#pragma unroll
    for (int j = 0; j < TN; ++j) red[ty * BN + tx * TN + j] = srow[j];
    __syncthreads();
    if (t < BN) {
      int col = colStart + t;
      if (col < N) {
        float s = 0.f;
#pragma unroll
        for (int r = 0; r < BM / TM; ++r) s += red[r * BN + t];
        int img = rowStart / NPP;   // BM=128 divides NPP=512: no straddle
        atomicAdd(out + (size_t)img * NCLS + col, s * (1.0f / NPP));
      }
    }
  }
}

// ---------------------------------------------------------------------------
extern "C" void kernel_launch(void* const* d_in, const int* in_sizes, int n_in,
                              void* d_out, int out_size, void* d_ws,
                              size_t ws_size, hipStream_t stream) {
  const float* x    = (const float*)d_in[0];
  const float* w_l0 = (const float*)d_in[1];
  const float* b_l0 = (const float*)d_in[2];
  const float* w_r0 = (const float*)d_in[3];
  const float* w_l1 = (const float*)d_in[4];
  const float* b_l1 = (const float*)d_in[5];
  const float* w_r1 = (const float*)d_in[6];
  const float* w_l2 = (const float*)d_in[7];
  const float* b_l2 = (const float*)d_in[8];
  const float* w_r2 = (const float*)d_in[9];
  float* out = (float*)d_out;

  char* ws = (char*)d_ws;
  // sq 32KB | idx 288KB | cand_v 18.0MB | cand_i(u16) 9.0MB | xs(bf16) 6.0MB
  // cand region dead after k_reduce_topk -> reused for agg/h0/h1.
  float*    sq     = (float*)(ws);
  int*      idx    = (int*)(ws + 32768);
  float*    cand_v = (float*)(ws + 327680);
  ushort_t* cand_i = (ushort_t*)(ws + 19202048);
  ushort_t* xs     = (ushort_t*)(ws + 28639232);
  float*    agg    = (float*)(ws + 327680);
  float*    h0     = (float*)(ws + 327680 + 8388608);
  float*    h1     = (float*)(ws + 327680 + 16777216);

  k_norms<<<2048, 256, 0, stream>>>(x, sq);
  k_split<<<(NN * FEAT) / 256, 256, 0, stream>>>(x, xs);
  k_dist_topk<<<dim3(64, 64), 256, 0, stream>>>(xs, sq, cand_v, cand_i);
  k_reduce_topk<<<2048, 256, 0, stream>>>(cand_v, cand_i, idx);
  k_zero<<<(NIMG * NCLS + 255) / 256, 256, 0, stream>>>(out, NIMG * NCLS);
  k_gather<<<2048, 256, 0, stream>>>(x, idx, agg, FEAT);
  k_sage_gemm<64, 64, 4, 4, false><<<dim3(HID / 64, NN / 64), 256, 0, stream>>>(
      agg, x, FEAT, FEAT, w_l0, w_r0, b_l0, h0, HID);
  k_gather<<<2048, 256, 0, stream>>>(h0, idx, agg, HID);
  k_sage_gemm<64, 64, 4, 4, false><<<dim3(HID / 64, NN / 64), 256, 0, stream>>>(
      agg, h0, HID, HID, w_l1, w_r1, b_l1, h1, HID);
  k_gather<<<2048, 256, 0, stream>>>(h1, idx, agg, HID);
  k_sage_gemm<128, 128, 8, 8, true><<<dim3(8, NN / 128), 256, 0, stream>>>(
      agg, h1, HID, HID, w_l2, w_r2, b_l2, out, NCLS);
}

// Round 3
// 468.691 us; speedup vs baseline: 3.0403x; 3.0403x over previous
//
#include <hip/hip_runtime.h>

#define NN   8192
#define FEAT 192
#define HID  256
#define NCLS 1000
#define KNN  9
#define NPP  512          // nodes per image (8192 / 16)
#define NIMG 16
#define KSPL 384          // split-bf16 K (hi|lo concatenated)
#define FINF 3.402823466e38f

typedef unsigned short ushort_t;
typedef __attribute__((ext_vector_type(8))) __bf16 bf16x8;
typedef __attribute__((ext_vector_type(4))) float f32x4;

#define ASYNC16(gptr, lptr)                                                  \
  __builtin_amdgcn_global_load_lds(                                          \
      (const __attribute__((address_space(1))) void*)(gptr),                 \
      (__attribute__((address_space(3))) void*)(lptr), 16, 0, 0)

// ---------------------------------------------------------------------------
__device__ __forceinline__ ushort_t f2bf_rne(float f) {
  unsigned u = __float_as_uint(f);
  u += 0x7FFF + ((u >> 16) & 1);          // round-to-nearest-even
  return (ushort_t)(u >> 16);
}

// sorted-ascending top-9 insertion; strict '<' keeps earlier entry on ties.
__device__ __forceinline__ void topk_insert(float (&tv)[KNN], int (&tc)[KNN],
                                            float v, int c) {
  if (v < tv[KNN - 1]) {
    tv[KNN - 1] = v; tc[KNN - 1] = c;
#pragma unroll
    for (int p = KNN - 1; p > 0; --p) {
      if (tv[p] < tv[p - 1]) {
        float fv = tv[p]; tv[p] = tv[p - 1]; tv[p - 1] = fv;
        int   fi = tc[p]; tc[p] = tc[p - 1]; tc[p - 1] = fi;
      }
    }
  }
}

// ---------------------------------------------------------------------------
__global__ __launch_bounds__(256) void k_norms(const float* __restrict__ x,
                                               float* __restrict__ sq) {
  int wid  = (blockIdx.x * 256 + threadIdx.x) >> 6;
  int lane = threadIdx.x & 63;
  if (wid >= NN) return;
  const float* row = x + (size_t)wid * FEAT;
  float s = 0.f;
  for (int f = lane; f < FEAT; f += 64) { float v = row[f]; s += v * v; }
#pragma unroll
  for (int off = 32; off > 0; off >>= 1) s += __shfl_down(s, off);
  if (lane == 0) sq[wid] = s;
}

// ---------------------------------------------------------------------------
// split-bf16: xs[i][0..191] = bf16(x), xs[i][192..383] = bf16(x - hi)
__global__ __launch_bounds__(256) void k_split(const float* __restrict__ x,
                                               ushort_t* __restrict__ xs) {
  int i = blockIdx.x * 256 + threadIdx.x;
  if (i >= NN * FEAT) return;
  int r = i / FEAT, c = i - r * FEAT;
  float v = x[i];
  ushort_t h = f2bf_rne(v);
  float hf = __uint_as_float((unsigned)h << 16);
  ushort_t l = f2bf_rne(v - hf);
  xs[(size_t)r * KSPL + c]        = h;
  xs[(size_t)r * KSPL + FEAT + c] = l;
}

// ---------------------------------------------------------------------------
// MFMA distance + per-colblock top-9. 128x128 tile, K=384 bf16 (hi|lo split).
// R3: named f32x4 accumulators (no array -> no scratch demotion),
// __launch_bounds__(256,2) caps regs at 256 (need ~200, zero spill),
// '#pragma unroll 1' on the K-loop. Staging/epilogue identical to R2.
__global__ __launch_bounds__(256, 2) void k_dist_topk(
    const ushort_t* __restrict__ xs, const float* __restrict__ sq,
    float* __restrict__ cand_v, ushort_t* __restrict__ cand_i) {
  __shared__ __align__(16) char smem[26624];
  ushort_t* As = (ushort_t*)smem;            // [128][32] (granule-swizzled)
  ushort_t* Bs = (ushort_t*)(smem + 8192);
  float*    Es = (float*)smem;               // wave w at +w*1088: [64][17]
  float*    Ms = (float*)(smem + 17408);     // [128][18] merge buf

  const int t    = threadIdx.x;
  const int lane = t & 63;
  const int w    = t >> 6;
  const int l15  = lane & 15, lq = lane >> 4;
  const int rowStart = blockIdx.y * 128;
  const int colStart = blockIdx.x * 128;
  const int mrow = (w >> 1) * 64;            // wave's row quadrant
  const int ncol = (w & 1) * 64;             // wave's col quadrant

  // staging geometry: chunk m = (w*2+q)*64 + lane; r = m>>2, granule = m&3,
  // swizzled global granule gs = g ^ (r&3); LDS stays linearly packed.
  const int m0 = w * 128 + lane;             // q=0 chunk; q=1 is m0+64
  const int r0 = m0 >> 2, r1 = r0 + 16;
  const int g0 = m0 & 3;
  const int gs0 = g0 ^ (r0 & 3);
  const int gs1 = g0 ^ (r1 & 3);
  const ushort_t* gA0 = xs + (size_t)(rowStart + r0) * KSPL + gs0 * 8;
  const ushort_t* gA1 = xs + (size_t)(rowStart + r1) * KSPL + gs1 * 8;
  const ushort_t* gB0 = xs + (size_t)(colStart + r0) * KSPL + gs0 * 8;
  const ushort_t* gB1 = xs + (size_t)(colStart + r1) * KSPL + gs1 * 8;
  ushort_t* lA = As + w * 1024;              // + q*512 elements
  ushort_t* lB = Bs + w * 1024;

  // fragment LDS offsets (swizzle-aware): phys granule = lq ^ (l15&3)
  const int pg = (lq ^ (l15 & 3)) * 8;
  int aoff[4], boff[4];
#pragma unroll
  for (int ti = 0; ti < 4; ++ti) aoff[ti] = (mrow + ti * 16 + l15) * 32 + pg;
#pragma unroll
  for (int tj = 0; tj < 4; ++tj) boff[tj] = (ncol + tj * 16 + l15) * 32 + pg;

  f32x4 c00 = {}, c01 = {}, c02 = {}, c03 = {};
  f32x4 c10 = {}, c11 = {}, c12 = {}, c13 = {};
  f32x4 c20 = {}, c21 = {}, c22 = {}, c23 = {};
  f32x4 c30 = {}, c31 = {}, c32 = {}, c33 = {};

#pragma unroll 1
  for (int kt = 0; kt < 12; ++kt) {
    const int k0 = kt * 32;
    ASYNC16(gA0 + k0, lA);
    ASYNC16(gA1 + k0, lA + 512);
    ASYNC16(gB0 + k0, lB);
    ASYNC16(gB1 + k0, lB + 512);
    __syncthreads();                         // drains vmcnt: tile visible
    bf16x8 a0 = *(const bf16x8*)(As + aoff[0]);
    bf16x8 a1 = *(const bf16x8*)(As + aoff[1]);
    bf16x8 a2 = *(const bf16x8*)(As + aoff[2]);
    bf16x8 a3 = *(const bf16x8*)(As + aoff[3]);
    bf16x8 b0 = *(const bf16x8*)(Bs + boff[0]);
    bf16x8 b1 = *(const bf16x8*)(Bs + boff[1]);
    bf16x8 b2 = *(const bf16x8*)(Bs + boff[2]);
    bf16x8 b3 = *(const bf16x8*)(Bs + boff[3]);
    c00 = __builtin_amdgcn_mfma_f32_16x16x32_bf16(a0, b0, c00, 0, 0, 0);
    c01 = __builtin_amdgcn_mfma_f32_16x16x32_bf16(a0, b1, c01, 0, 0, 0);
    c02 = __builtin_amdgcn_mfma_f32_16x16x32_bf16(a0, b2, c02, 0, 0, 0);
    c03 = __builtin_amdgcn_mfma_f32_16x16x32_bf16(a0, b3, c03, 0, 0, 0);
    c10 = __builtin_amdgcn_mfma_f32_16x16x32_bf16(a1, b0, c10, 0, 0, 0);
    c11 = __builtin_amdgcn_mfma_f32_16x16x32_bf16(a1, b1, c11, 0, 0, 0);
    c12 = __builtin_amdgcn_mfma_f32_16x16x32_bf16(a1, b2, c12, 0, 0, 0);
    c13 = __builtin_amdgcn_mfma_f32_16x16x32_bf16(a1, b3, c13, 0, 0, 0);
    c20 = __builtin_amdgcn_mfma_f32_16x16x32_bf16(a2, b0, c20, 0, 0, 0);
    c21 = __builtin_amdgcn_mfma_f32_16x16x32_bf16(a2, b1, c21, 0, 0, 0);
    c22 = __builtin_amdgcn_mfma_f32_16x16x32_bf16(a2, b2, c22, 0, 0, 0);
    c23 = __builtin_amdgcn_mfma_f32_16x16x32_bf16(a2, b3, c23, 0, 0, 0);
    c30 = __builtin_amdgcn_mfma_f32_16x16x32_bf16(a3, b0, c30, 0, 0, 0);
    c31 = __builtin_amdgcn_mfma_f32_16x16x32_bf16(a3, b1, c31, 0, 0, 0);
    c32 = __builtin_amdgcn_mfma_f32_16x16x32_bf16(a3, b2, c32, 0, 0, 0);
    c33 = __builtin_amdgcn_mfma_f32_16x16x32_bf16(a3, b3, c33, 0, 0, 0);
    __syncthreads();                         // all reads done before re-stage
  }

  // ---- epilogue: v = sq[j] - 2*dot, per-row top-9 over this block's cols
  float tv[KNN]; int tc[KNN];
#pragma unroll
  for (int n = 0; n < KNN; ++n) { tv[n] = FINF; tc[n] = -1; }

  float* Ew = Es + w * 1088;                 // this wave's [64][17] scratch

#define EPI_ROW(TI, CV)                                                      \
  do {                                                                       \
    f32x4 v_ = (CV);                                                         \
    Ew[((TI) * 16 + lq * 4 + 0) * 17 + l15] = sqv - 2.0f * v_.x;             \
    Ew[((TI) * 16 + lq * 4 + 1) * 17 + l15] = sqv - 2.0f * v_.y;             \
    Ew[((TI) * 16 + lq * 4 + 2) * 17 + l15] = sqv - 2.0f * v_.z;             \
    Ew[((TI) * 16 + lq * 4 + 3) * 17 + l15] = sqv - 2.0f * v_.w;             \
  } while (0)

#define EPI_TILE(TJ, C0, C1, C2, C3)                                         \
  do {                                                                       \
    float sqv = sq[colStart + ncol + (TJ) * 16 + l15];                       \
    __syncthreads();                                                         \
    EPI_ROW(0, C0); EPI_ROW(1, C1); EPI_ROW(2, C2); EPI_ROW(3, C3);          \
    __syncthreads();                                                         \
    int cbase = colStart + ncol + (TJ) * 16;                                 \
    _Pragma("unroll")                                                        \
    for (int c = 0; c < 16; ++c)                                             \
      topk_insert(tv, tc, Ew[lane * 17 + c], cbase + c);                     \
  } while (0)

  EPI_TILE(0, c00, c10, c20, c30);
  EPI_TILE(1, c01, c11, c21, c31);
  EPI_TILE(2, c02, c12, c22, c32);
  EPI_TILE(3, c03, c13, c23, c33);

  // merge the two waves sharing each row half, write candidates
  __syncthreads();
  if (w & 1) {
#pragma unroll
    for (int n = 0; n < KNN; ++n) {
      Ms[(mrow + lane) * 18 + n]     = tv[n];
      Ms[(mrow + lane) * 18 + 9 + n] = __int_as_float(tc[n]);
    }
  }
  __syncthreads();
  if (!(w & 1)) {
#pragma unroll
    for (int n = 0; n < KNN; ++n)
      topk_insert(tv, tc, Ms[(mrow + lane) * 18 + n],
                  __float_as_int(Ms[(mrow + lane) * 18 + 9 + n]));
    size_t base = (((size_t)(rowStart + mrow + lane)) * 64 + blockIdx.x) * KNN;
#pragma unroll
    for (int n = 0; n < KNN; ++n) {
      cand_v[base + n] = tv[n];
      cand_i[base + n] = (ushort_t)tc[n];
    }
  }
}

// ---------------------------------------------------------------------------
// one wave per row: merge 64 colblocks x 9 = 576 candidates -> final 9 idx
__global__ __launch_bounds__(256) void k_reduce_topk(
    const float* __restrict__ cand_v, const ushort_t* __restrict__ cand_i,
    int* __restrict__ idx) {
  int wid  = (blockIdx.x * 256 + threadIdx.x) >> 6;
  int lane = threadIdx.x & 63;
  if (wid >= NN) return;
  const float*    cv = cand_v + (size_t)wid * 576;
  const ushort_t* ci = cand_i + (size_t)wid * 576;
  float tv[KNN]; int tc[KNN];
#pragma unroll
  for (int n = 0; n < KNN; ++n) { tv[n] = FINF; tc[n] = -1; }
#pragma unroll
  for (int m = 0; m < KNN; ++m)
    topk_insert(tv, tc, cv[lane + 64 * m], (int)ci[lane + 64 * m]);

  for (int r = 0; r < KNN; ++r) {
    float bv = tv[0]; int bc = tc[0];
#pragma unroll
    for (int n = 1; n < KNN; ++n)
      if (tv[n] < bv) { bv = tv[n]; bc = tc[n]; }
#pragma unroll
    for (int off = 32; off > 0; off >>= 1) {
      float ov = __shfl_xor(bv, off);
      int   oc = __shfl_xor(bc, off);
      if (ov < bv || (ov == bv && oc < bc)) { bv = ov; bc = oc; }
    }
#pragma unroll
    for (int n = 0; n < KNN; ++n)
      if (tc[n] == bc) tv[n] = FINF;
    if (lane == 0) idx[wid * KNN + r] = bc;
  }
}

// ---------------------------------------------------------------------------
__global__ __launch_bounds__(256) void k_gather(
    const float* __restrict__ h, const int* __restrict__ idx,
    float* __restrict__ agg, int C) {
  int wid  = (blockIdx.x * 256 + threadIdx.x) >> 6;
  int lane = threadIdx.x & 63;
  if (wid >= NN) return;
  int nb[KNN];
#pragma unroll
  for (int n = 0; n < KNN; ++n) nb[n] = idx[wid * KNN + n];
  for (int f = lane; f < C; f += 64) {
    float s = 0.f;
#pragma unroll
    for (int n = 0; n < KNN; ++n) s += h[(size_t)nb[n] * C + f];
    agg[(size_t)wid * C + f] = s * (1.0f / KNN);
  }
}

// ---------------------------------------------------------------------------
__global__ void k_zero(float* __restrict__ out, int n) {
  int i = blockIdx.x * 256 + threadIdx.x;
  if (i < n) out[i] = 0.f;
}

// ---------------------------------------------------------------------------
// h = relu([A1|A2] @ [W1;W2] + bias); POOL: fused global mean pool (atomic)
template <int BM, int BN, int TM, int TN, bool POOL>
__global__ __launch_bounds__(256) void k_sage_gemm(
    const float* __restrict__ A1, const float* __restrict__ A2, int K1, int K2,
    const float* __restrict__ W1, const float* __restrict__ W2,
    const float* __restrict__ bias, float* __restrict__ out, int N) {
  constexpr int BK = 8;
  __shared__ float As[BK][BM];
  __shared__ float Bs[BK][BN];
  __shared__ float red[POOL ? (BM / TM) * BN : 1];

  const int t  = threadIdx.x;
  const int tx = t & 15, ty = t >> 4;
  const int rowStart = blockIdx.y * BM;
  const int colStart = blockIdx.x * BN;

  const int  alr = t >> 1, alk = (t & 1) * 4;
  const bool aact = t < BM * 2;
  constexpr int BW = BN / 4;
  const int  bkr = t / BW, bnc = (t % BW) * 4;
  const bool bact = t < BK * BW;

  float acc[TM][TN] = {};
  const int KT = K1 + K2;

  for (int k0 = 0; k0 < KT; k0 += BK) {
    float4 av = {0, 0, 0, 0}, bv = {0, 0, 0, 0};
    if (aact) {
      int kk = k0 + alk;
      const float* src = (kk < K1)
          ? A1 + (size_t)(rowStart + alr) * K1 + kk
          : A2 + (size_t)(rowStart + alr) * K2 + (kk - K1);
      av = *(const float4*)src;
    }
    if (bact) {
      int kk = k0 + bkr;
      const float* wsrc = (kk < K1) ? W1 + (size_t)kk * N
                                    : W2 + (size_t)(kk - K1) * N;
      int col = colStart + bnc;
      if (col < N) bv = *(const float4*)(wsrc + col);
    }
    __syncthreads();
    if (aact) {
      As[alk + 0][alr] = av.x; As[alk + 1][alr] = av.y;
      As[alk + 2][alr] = av.z; As[alk + 3][alr] = av.w;
    }
    if (bact) *(float4*)&Bs[bkr][bnc] = bv;
    __syncthreads();
#pragma unroll
    for (int k = 0; k < BK; ++k) {
      float a[TM], b[TN];
#pragma unroll
      for (int i = 0; i < TM; i += 4)
        *(float4*)&a[i] = *(const float4*)&As[k][ty * TM + i];
#pragma unroll
      for (int j = 0; j < TN; j += 4)
        *(float4*)&b[j] = *(const float4*)&Bs[k][tx * TN + j];
#pragma unroll
      for (int i = 0; i < TM; ++i)
#pragma unroll
        for (int j = 0; j < TN; ++j)
          acc[i][j] = fmaf(a[i], b[j], acc[i][j]);
    }
  }

  float bvals[TN];
#pragma unroll
  for (int j = 0; j < TN; ++j) {
    int col = colStart + tx * TN + j;
    bvals[j] = (col < N) ? bias[col] : 0.f;
  }

  if (!POOL) {
#pragma unroll
    for (int i = 0; i < TM; ++i) {
      int row = rowStart + ty * TM + i;
#pragma unroll
      for (int j = 0; j < TN; ++j) {
        int col = colStart + tx * TN + j;
        if (col < N)
          out[(size_t)row * N + col] = fmaxf(acc[i][j] + bvals[j], 0.f);
      }
    }
  } else {
    float srow[TN];
#pragma unroll
    for (int j = 0; j < TN; ++j) {
      float s = 0.f;
#pragma unroll
      for (int i = 0; i < TM; ++i) s += fmaxf(acc[i][j] + bvals[j], 0.f);
      srow[j] = s;
    }
#pragma unroll
    for (int j = 0; j < TN; ++j) red[ty * BN + tx * TN + j] = srow[j];
    __syncthreads();
    if (t < BN) {
      int col = colStart + t;
      if (col < N) {
        float s = 0.f;
#pragma unroll
        for (int r = 0; r < BM / TM; ++r) s += red[r * BN + t];
        int img = rowStart / NPP;   // BM=128 divides NPP=512: no straddle
        atomicAdd(out + (size_t)img * NCLS + col, s * (1.0f / NPP));
      }
    }
  }
}

// ---------------------------------------------------------------------------
extern "C" void kernel_launch(void* const* d_in, const int* in_sizes, int n_in,
                              void* d_out, int out_size, void* d_ws,
                              size_t ws_size, hipStream_t stream) {
  const float* x    = (const float*)d_in[0];
  const float* w_l0 = (const float*)d_in[1];
  const float* b_l0 = (const float*)d_in[2];
  const float* w_r0 = (const float*)d_in[3];
  const float* w_l1 = (const float*)d_in[4];
  const float* b_l1 = (const float*)d_in[5];
  const float* w_r1 = (const float*)d_in[6];
  const float* w_l2 = (const float*)d_in[7];
  const float* b_l2 = (const float*)d_in[8];
  const float* w_r2 = (const float*)d_in[9];
  float* out = (float*)d_out;

  char* ws = (char*)d_ws;
  // sq 32KB | idx 288KB | cand_v 18.0MB | cand_i(u16) 9.0MB | xs(bf16) 6.0MB
  // cand region dead after k_reduce_topk -> reused for agg/h0/h1.
  float*    sq     = (float*)(ws);
  int*      idx    = (int*)(ws + 32768);
  float*    cand_v = (float*)(ws + 327680);
  ushort_t* cand_i = (ushort_t*)(ws + 19202048);
  ushort_t* xs     = (ushort_t*)(ws + 28639232);
  float*    agg    = (float*)(ws + 327680);
  float*    h0     = (float*)(ws + 327680 + 8388608);
  float*    h1     = (float*)(ws + 327680 + 16777216);

  k_norms<<<2048, 256, 0, stream>>>(x, sq);
  k_split<<<(NN * FEAT) / 256, 256, 0, stream>>>(x, xs);
  k_dist_topk<<<dim3(64, 64), 256, 0, stream>>>(xs, sq, cand_v, cand_i);
  k_reduce_topk<<<2048, 256, 0, stream>>>(cand_v, cand_i, idx);
  k_zero<<<(NIMG * NCLS + 255) / 256, 256, 0, stream>>>(out, NIMG * NCLS);
  k_gather<<<2048, 256, 0, stream>>>(x, idx, agg, FEAT);
  k_sage_gemm<64, 64, 4, 4, false><<<dim3(HID / 64, NN / 64), 256, 0, stream>>>(
      agg, x, FEAT, FEAT, w_l0, w_r0, b_l0, h0, HID);
  k_gather<<<2048, 256, 0, stream>>>(h0, idx, agg, HID);
  k_sage_gemm<64, 64, 4, 4, false><<<dim3(HID / 64, NN / 64), 256, 0, stream>>>(
      agg, h0, HID, HID, w_l1, w_r1, b_l1, h1, HID);
  k_gather<<<2048, 256, 0, stream>>>(h1, idx, agg, HID);
  k_sage_gemm<128, 128, 8, 8, true><<<dim3(8, NN / 128), 256, 0, stream>>>(
      agg, h1, HID, HID, w_l2, w_r2, b_l2, out, NCLS);
}

// Round 4
// 312.455 us; speedup vs baseline: 4.5605x; 1.5000x over previous
//
#include <hip/hip_runtime.h>

#define NN   8192
#define FEAT 192
#define HID  256
#define NCLS 1000
#define KNN  9
#define NPP  512          // nodes per image (8192 / 16)
#define NIMG 16
#define KSPL 384          // split-bf16 K (hi|lo concatenated)
#define FINF 3.402823466e38f

typedef unsigned short ushort_t;
typedef __attribute__((ext_vector_type(8))) __bf16 bf16x8;
typedef __attribute__((ext_vector_type(4))) float f32x4;

#define ASYNC16(gptr, lptr)                                                  \
  __builtin_amdgcn_global_load_lds(                                          \
      (const __attribute__((address_space(1))) void*)(gptr),                 \
      (__attribute__((address_space(3))) void*)(lptr), 16, 0, 0)

// ---------------------------------------------------------------------------
__device__ __forceinline__ ushort_t f2bf_rne(float f) {
  unsigned u = __float_as_uint(f);
  u += 0x7FFF + ((u >> 16) & 1);          // round-to-nearest-even
  return (ushort_t)(u >> 16);
}
__device__ __forceinline__ float bf2f(ushort_t u) {
  return __uint_as_float((unsigned)u << 16);
}

// sorted-ascending top-9 insertion; strict '<' keeps earlier entry on ties.
__device__ __forceinline__ void topk_insert(float (&tv)[KNN], int (&tc)[KNN],
                                            float v, int c) {
  if (v < tv[KNN - 1]) {
    tv[KNN - 1] = v; tc[KNN - 1] = c;
#pragma unroll
    for (int p = KNN - 1; p > 0; --p) {
      if (tv[p] < tv[p - 1]) {
        float fv = tv[p]; tv[p] = tv[p - 1]; tv[p - 1] = fv;
        int   fi = tc[p]; tc[p] = tc[p - 1]; tc[p - 1] = fi;
      }
    }
  }
}

// ---------------------------------------------------------------------------
__global__ __launch_bounds__(256) void k_norms(const float* __restrict__ x,
                                               float* __restrict__ sq) {
  int wid  = (blockIdx.x * 256 + threadIdx.x) >> 6;
  int lane = threadIdx.x & 63;
  if (wid >= NN) return;
  const float* row = x + (size_t)wid * FEAT;
  float s = 0.f;
  for (int f = lane; f < FEAT; f += 64) { float v = row[f]; s += v * v; }
#pragma unroll
  for (int off = 32; off > 0; off >>= 1) s += __shfl_down(s, off);
  if (lane == 0) sq[wid] = s;
}

// ---------------------------------------------------------------------------
// split-bf16: xs[i][0..191] = bf16(x), xs[i][192..383] = bf16(x - hi)
__global__ __launch_bounds__(256) void k_split(const float* __restrict__ x,
                                               ushort_t* __restrict__ xs) {
  int i = blockIdx.x * 256 + threadIdx.x;
  if (i >= NN * FEAT) return;
  int r = i / FEAT, c = i - r * FEAT;
  float v = x[i];
  ushort_t h = f2bf_rne(v);
  float hf = bf2f(h);
  ushort_t l = f2bf_rne(v - hf);
  xs[(size_t)r * KSPL + c]        = h;
  xs[(size_t)r * KSPL + FEAT + c] = l;
}

// ---------------------------------------------------------------------------
// MFMA distance + per-colblock top-9 (unchanged from R3: 168 us).
__global__ __launch_bounds__(256, 2) void k_dist_topk(
    const ushort_t* __restrict__ xs, const float* __restrict__ sq,
    float* __restrict__ cand_v, ushort_t* __restrict__ cand_i) {
  __shared__ __align__(16) char smem[26624];
  ushort_t* As = (ushort_t*)smem;            // [128][32] (granule-swizzled)
  ushort_t* Bs = (ushort_t*)(smem + 8192);
  float*    Es = (float*)smem;               // wave w at +w*1088: [64][17]
  float*    Ms = (float*)(smem + 17408);     // [128][18] merge buf

  const int t    = threadIdx.x;
  const int lane = t & 63;
  const int w    = t >> 6;
  const int l15  = lane & 15, lq = lane >> 4;
  const int rowStart = blockIdx.y * 128;
  const int colStart = blockIdx.x * 128;
  const int mrow = (w >> 1) * 64;            // wave's row quadrant
  const int ncol = (w & 1) * 64;             // wave's col quadrant

  const int m0 = w * 128 + lane;             // q=0 chunk; q=1 is m0+64
  const int r0 = m0 >> 2, r1 = r0 + 16;
  const int g0 = m0 & 3;
  const int gs0 = g0 ^ (r0 & 3);
  const int gs1 = g0 ^ (r1 & 3);
  const ushort_t* gA0 = xs + (size_t)(rowStart + r0) * KSPL + gs0 * 8;
  const ushort_t* gA1 = xs + (size_t)(rowStart + r1) * KSPL + gs1 * 8;
  const ushort_t* gB0 = xs + (size_t)(colStart + r0) * KSPL + gs0 * 8;
  const ushort_t* gB1 = xs + (size_t)(colStart + r1) * KSPL + gs1 * 8;
  ushort_t* lA = As + w * 1024;              // + q*512 elements
  ushort_t* lB = Bs + w * 1024;

  const int pg = (lq ^ (l15 & 3)) * 8;
  int aoff[4], boff[4];
#pragma unroll
  for (int ti = 0; ti < 4; ++ti) aoff[ti] = (mrow + ti * 16 + l15) * 32 + pg;
#pragma unroll
  for (int tj = 0; tj < 4; ++tj) boff[tj] = (ncol + tj * 16 + l15) * 32 + pg;

  f32x4 c00 = {}, c01 = {}, c02 = {}, c03 = {};
  f32x4 c10 = {}, c11 = {}, c12 = {}, c13 = {};
  f32x4 c20 = {}, c21 = {}, c22 = {}, c23 = {};
  f32x4 c30 = {}, c31 = {}, c32 = {}, c33 = {};

#pragma unroll 1
  for (int kt = 0; kt < 12; ++kt) {
    const int k0 = kt * 32;
    ASYNC16(gA0 + k0, lA);
    ASYNC16(gA1 + k0, lA + 512);
    ASYNC16(gB0 + k0, lB);
    ASYNC16(gB1 + k0, lB + 512);
    __syncthreads();
    bf16x8 a0 = *(const bf16x8*)(As + aoff[0]);
    bf16x8 a1 = *(const bf16x8*)(As + aoff[1]);
    bf16x8 a2 = *(const bf16x8*)(As + aoff[2]);
    bf16x8 a3 = *(const bf16x8*)(As + aoff[3]);
    bf16x8 b0 = *(const bf16x8*)(Bs + boff[0]);
    bf16x8 b1 = *(const bf16x8*)(Bs + boff[1]);
    bf16x8 b2 = *(const bf16x8*)(Bs + boff[2]);
    bf16x8 b3 = *(const bf16x8*)(Bs + boff[3]);
    c00 = __builtin_amdgcn_mfma_f32_16x16x32_bf16(a0, b0, c00, 0, 0, 0);
    c01 = __builtin_amdgcn_mfma_f32_16x16x32_bf16(a0, b1, c01, 0, 0, 0);
    c02 = __builtin_amdgcn_mfma_f32_16x16x32_bf16(a0, b2, c02, 0, 0, 0);
    c03 = __builtin_amdgcn_mfma_f32_16x16x32_bf16(a0, b3, c03, 0, 0, 0);
    c10 = __builtin_amdgcn_mfma_f32_16x16x32_bf16(a1, b0, c10, 0, 0, 0);
    c11 = __builtin_amdgcn_mfma_f32_16x16x32_bf16(a1, b1, c11, 0, 0, 0);
    c12 = __builtin_amdgcn_mfma_f32_16x16x32_bf16(a1, b2, c12, 0, 0, 0);
    c13 = __builtin_amdgcn_mfma_f32_16x16x32_bf16(a1, b3, c13, 0, 0, 0);
    c20 = __builtin_amdgcn_mfma_f32_16x16x32_bf16(a2, b0, c20, 0, 0, 0);
    c21 = __builtin_amdgcn_mfma_f32_16x16x32_bf16(a2, b1, c21, 0, 0, 0);
    c22 = __builtin_amdgcn_mfma_f32_16x16x32_bf16(a2, b2, c22, 0, 0, 0);
    c23 = __builtin_amdgcn_mfma_f32_16x16x32_bf16(a2, b3, c23, 0, 0, 0);
    c30 = __builtin_amdgcn_mfma_f32_16x16x32_bf16(a3, b0, c30, 0, 0, 0);
    c31 = __builtin_amdgcn_mfma_f32_16x16x32_bf16(a3, b1, c31, 0, 0, 0);
    c32 = __builtin_amdgcn_mfma_f32_16x16x32_bf16(a3, b2, c32, 0, 0, 0);
    c33 = __builtin_amdgcn_mfma_f32_16x16x32_bf16(a3, b3, c33, 0, 0, 0);
    __syncthreads();
  }

  float tv[KNN]; int tc[KNN];
#pragma unroll
  for (int n = 0; n < KNN; ++n) { tv[n] = FINF; tc[n] = -1; }

  float* Ew = Es + w * 1088;

#define EPI_ROW(TI, CV)                                                      \
  do {                                                                       \
    f32x4 v_ = (CV);                                                         \
    Ew[((TI) * 16 + lq * 4 + 0) * 17 + l15] = sqv - 2.0f * v_.x;             \
    Ew[((TI) * 16 + lq * 4 + 1) * 17 + l15] = sqv - 2.0f * v_.y;             \
    Ew[((TI) * 16 + lq * 4 + 2) * 17 + l15] = sqv - 2.0f * v_.z;             \
    Ew[((TI) * 16 + lq * 4 + 3) * 17 + l15] = sqv - 2.0f * v_.w;             \
  } while (0)

#define EPI_TILE(TJ, C0, C1, C2, C3)                                         \
  do {                                                                       \
    float sqv = sq[colStart + ncol + (TJ) * 16 + l15];                       \
    __syncthreads();                                                         \
    EPI_ROW(0, C0); EPI_ROW(1, C1); EPI_ROW(2, C2); EPI_ROW(3, C3);          \
    __syncthreads();                                                         \
    int cbase = colStart + ncol + (TJ) * 16;                                 \
    _Pragma("unroll")                                                        \
    for (int c = 0; c < 16; ++c)                                             \
      topk_insert(tv, tc, Ew[lane * 17 + c], cbase + c);                     \
  } while (0)

  EPI_TILE(0, c00, c10, c20, c30);
  EPI_TILE(1, c01, c11, c21, c31);
  EPI_TILE(2, c02, c12, c22, c32);
  EPI_TILE(3, c03, c13, c23, c33);

  __syncthreads();
  if (w & 1) {
#pragma unroll
    for (int n = 0; n < KNN; ++n) {
      Ms[(mrow + lane) * 18 + n]     = tv[n];
      Ms[(mrow + lane) * 18 + 9 + n] = __int_as_float(tc[n]);
    }
  }
  __syncthreads();
  if (!(w & 1)) {
#pragma unroll
    for (int n = 0; n < KNN; ++n)
      topk_insert(tv, tc, Ms[(mrow + lane) * 18 + n],
                  __float_as_int(Ms[(mrow + lane) * 18 + 9 + n]));
    size_t base = (((size_t)(rowStart + mrow + lane)) * 64 + blockIdx.x) * KNN;
#pragma unroll
    for (int n = 0; n < KNN; ++n) {
      cand_v[base + n] = tv[n];
      cand_i[base + n] = (ushort_t)tc[n];
    }
  }
}

// ---------------------------------------------------------------------------
__global__ __launch_bounds__(256) void k_reduce_topk(
    const float* __restrict__ cand_v, const ushort_t* __restrict__ cand_i,
    int* __restrict__ idx) {
  int wid  = (blockIdx.x * 256 + threadIdx.x) >> 6;
  int lane = threadIdx.x & 63;
  if (wid >= NN) return;
  const float*    cv = cand_v + (size_t)wid * 576;
  const ushort_t* ci = cand_i + (size_t)wid * 576;
  float tv[KNN]; int tc[KNN];
#pragma unroll
  for (int n = 0; n < KNN; ++n) { tv[n] = FINF; tc[n] = -1; }
#pragma unroll
  for (int m = 0; m < KNN; ++m)
    topk_insert(tv, tc, cv[lane + 64 * m], (int)ci[lane + 64 * m]);

  for (int r = 0; r < KNN; ++r) {
    float bv = tv[0]; int bc = tc[0];
#pragma unroll
    for (int n = 1; n < KNN; ++n)
      if (tv[n] < bv) { bv = tv[n]; bc = tc[n]; }
#pragma unroll
    for (int off = 32; off > 0; off >>= 1) {
      float ov = __shfl_xor(bv, off);
      int   oc = __shfl_xor(bc, off);
      if (ov < bv || (ov == bv && oc < bc)) { bv = ov; bc = oc; }
    }
#pragma unroll
    for (int n = 0; n < KNN; ++n)
      if (tc[n] == bc) tv[n] = FINF;
    if (lane == 0) idx[wid * KNN + r] = bc;
  }
}

// ---------------------------------------------------------------------------
// WT_l[n][k] = [w_l ; w_r]^T in bf16; L2 padded to 1024 rows (zero fill).
__global__ __launch_bounds__(256) void k_cast_w(
    const float* __restrict__ w_l0, const float* __restrict__ w_r0,
    const float* __restrict__ w_l1, const float* __restrict__ w_r1,
    const float* __restrict__ w_l2, const float* __restrict__ w_r2,
    ushort_t* __restrict__ WT0, ushort_t* __restrict__ WT1,
    ushort_t* __restrict__ WT2) {
  int i = blockIdx.x * 256 + threadIdx.x;
  if (i < 98304) {                               // 256 x 384
    int n = i / 384, k = i - n * 384;
    float v = (k < 192) ? w_l0[k * 256 + n] : w_r0[(k - 192) * 256 + n];
    WT0[i] = f2bf_rne(v);
  } else if (i < 98304 + 131072) {               // 256 x 512
    int j = i - 98304;
    int n = j / 512, k = j - n * 512;
    float v = (k < 256) ? w_l1[k * 256 + n] : w_r1[(k - 256) * 256 + n];
    WT1[j] = f2bf_rne(v);
  } else {                                       // 1024 x 512 (rows>=1000: 0)
    int j = i - (98304 + 131072);
    int n = j / 512, k = j - n * 512;
    float v = 0.f;
    if (n < NCLS)
      v = (k < 256) ? w_l2[k * NCLS + n] : w_r2[(k - 256) * NCLS + n];
    WT2[j] = f2bf_rne(v);
  }
}

// ---------------------------------------------------------------------------
// layer-0 input build: Ab0[row][0..191] = bf16(mean9 x), [192..383] = bf16(x)
__global__ __launch_bounds__(256) void k_gather_l0(
    const float* __restrict__ x, const int* __restrict__ idx,
    ushort_t* __restrict__ Ab0) {
  int wid  = (blockIdx.x * 256 + threadIdx.x) >> 6;
  int lane = threadIdx.x & 63;
  if (wid >= NN) return;
  int nb[KNN];
#pragma unroll
  for (int n = 0; n < KNN; ++n) nb[n] = idx[wid * KNN + n];
#pragma unroll
  for (int f = lane; f < FEAT; f += 64) {
    float s = 0.f;
#pragma unroll
    for (int n = 0; n < KNN; ++n) s += x[(size_t)nb[n] * FEAT + f];
    Ab0[(size_t)wid * KSPL + f]        = f2bf_rne(s * (1.0f / KNN));
    Ab0[(size_t)wid * KSPL + FEAT + f] = f2bf_rne(x[(size_t)wid * FEAT + f]);
  }
}

// layer-1/2 agg build: hsrc = Ab+256 (bf16, row stride 512); adst = Ab cols 0..255
__global__ __launch_bounds__(256) void k_gather_h(
    const ushort_t* __restrict__ hsrc, const int* __restrict__ idx,
    ushort_t* __restrict__ adst) {
  int wid  = (blockIdx.x * 256 + threadIdx.x) >> 6;
  int lane = threadIdx.x & 63;
  if (wid >= NN) return;
  int nb[KNN];
#pragma unroll
  for (int n = 0; n < KNN; ++n) nb[n] = idx[wid * KNN + n];
#pragma unroll
  for (int f = lane; f < HID; f += 64) {
    float s = 0.f;
#pragma unroll
    for (int n = 0; n < KNN; ++n) s += bf2f(hsrc[(size_t)nb[n] * 512 + f]);
    adst[(size_t)wid * 512 + f] = f2bf_rne(s * (1.0f / KNN));
  }
}

// ---------------------------------------------------------------------------
__global__ void k_zero(float* __restrict__ out, int n) {
  int i = blockIdx.x * 256 + threadIdx.x;
  if (i < n) out[i] = 0.f;
}

// ---------------------------------------------------------------------------
// bf16 MFMA SAGE layer, BM=128 BN=64, N=256. hdst = next-layer Ab + 256.
// C[row][col] = relu( dot(Ab_row, WT_col) + bias[col] ) -> bf16.
__global__ __launch_bounds__(256, 4) void k_sage64(
    const ushort_t* __restrict__ Ab, const ushort_t* __restrict__ WT,
    const float* __restrict__ bias, ushort_t* __restrict__ hdst, int KT) {
  __shared__ __align__(16) char smem[12288];
  ushort_t* As = (ushort_t*)smem;            // [128][32]
  ushort_t* Bs = (ushort_t*)(smem + 8192);   // [64][32]

  const int t    = threadIdx.x;
  const int lane = t & 63;
  const int w    = t >> 6;
  const int l15  = lane & 15, lq = lane >> 4;
  const int rowStart = blockIdx.y * 128;
  const int colStart = blockIdx.x * 64;
  const int mrow = (w >> 1) * 64;
  const int ncol = (w & 1) * 32;

  // A: chunks m = t (rows 0..63) and t+256 (rows 64..127); B: chunk m = t.
  const int rA0 = t >> 2, rA1 = rA0 + 64;
  const int g   = t & 3;
  const int gsA0 = g ^ (rA0 & 3), gsA1 = g ^ (rA1 & 3);
  const ushort_t* gA0 = Ab + (size_t)(rowStart + rA0) * KT + gsA0 * 8;
  const ushort_t* gA1 = Ab + (size_t)(rowStart + rA1) * KT + gsA1 * 8;
  const ushort_t* gB0 = WT + (size_t)(colStart + rA0) * KT + gsA0 * 8;
  ushort_t* lA0 = As + w * 512;
  ushort_t* lA1 = As + 2048 + w * 512;
  ushort_t* lB0 = Bs + w * 512;

  const int pg = (lq ^ (l15 & 3)) * 8;
  int aoff[4], boff[2];
#pragma unroll
  for (int ti = 0; ti < 4; ++ti) aoff[ti] = (mrow + ti * 16 + l15) * 32 + pg;
#pragma unroll
  for (int tj = 0; tj < 2; ++tj) boff[tj] = (ncol + tj * 16 + l15) * 32 + pg;

  f32x4 c00 = {}, c01 = {};
  f32x4 c10 = {}, c11 = {};
  f32x4 c20 = {}, c21 = {};
  f32x4 c30 = {}, c31 = {};

  const int nkt = KT >> 5;
#pragma unroll 1
  for (int kt = 0; kt < nkt; ++kt) {
    const int k0 = kt * 32;
    ASYNC16(gA0 + k0, lA0);
    ASYNC16(gA1 + k0, lA1);
    ASYNC16(gB0 + k0, lB0);
    __syncthreads();
    bf16x8 a0 = *(const bf16x8*)(As + aoff[0]);
    bf16x8 a1 = *(const bf16x8*)(As + aoff[1]);
    bf16x8 a2 = *(const bf16x8*)(As + aoff[2]);
    bf16x8 a3 = *(const bf16x8*)(As + aoff[3]);
    bf16x8 b0 = *(const bf16x8*)(Bs + boff[0]);
    bf16x8 b1 = *(const bf16x8*)(Bs + boff[1]);
    c00 = __builtin_amdgcn_mfma_f32_16x16x32_bf16(a0, b0, c00, 0, 0, 0);
    c01 = __builtin_amdgcn_mfma_f32_16x16x32_bf16(a0, b1, c01, 0, 0, 0);
    c10 = __builtin_amdgcn_mfma_f32_16x16x32_bf16(a1, b0, c10, 0, 0, 0);
    c11 = __builtin_amdgcn_mfma_f32_16x16x32_bf16(a1, b1, c11, 0, 0, 0);
    c20 = __builtin_amdgcn_mfma_f32_16x16x32_bf16(a2, b0, c20, 0, 0, 0);
    c21 = __builtin_amdgcn_mfma_f32_16x16x32_bf16(a2, b1, c21, 0, 0, 0);
    c30 = __builtin_amdgcn_mfma_f32_16x16x32_bf16(a3, b0, c30, 0, 0, 0);
    c31 = __builtin_amdgcn_mfma_f32_16x16x32_bf16(a3, b1, c31, 0, 0, 0);
    __syncthreads();
  }

  const float bv0 = bias[colStart + ncol + l15];
  const float bv1 = bias[colStart + ncol + 16 + l15];

#define S64_STORE(TI, TJ, CV, BV)                                            \
  do {                                                                       \
    f32x4 v_ = (CV);                                                         \
    int col_ = colStart + ncol + (TJ) * 16 + l15;                            \
    size_t rb_ = (size_t)(rowStart + mrow + (TI) * 16 + lq * 4);             \
    hdst[(rb_ + 0) * 512 + col_] = f2bf_rne(fmaxf(v_.x + (BV), 0.f));        \
    hdst[(rb_ + 1) * 512 + col_] = f2bf_rne(fmaxf(v_.y + (BV), 0.f));        \
    hdst[(rb_ + 2) * 512 + col_] = f2bf_rne(fmaxf(v_.z + (BV), 0.f));        \
    hdst[(rb_ + 3) * 512 + col_] = f2bf_rne(fmaxf(v_.w + (BV), 0.f));        \
  } while (0)

  S64_STORE(0, 0, c00, bv0); S64_STORE(0, 1, c01, bv1);
  S64_STORE(1, 0, c10, bv0); S64_STORE(1, 1, c11, bv1);
  S64_STORE(2, 0, c20, bv0); S64_STORE(2, 1, c21, bv1);
  S64_STORE(3, 0, c30, bv0); S64_STORE(3, 1, c31, bv1);
}

// ---------------------------------------------------------------------------
// bf16 MFMA layer-2 + fused global mean pool. BM=128 BN=128, N=1024 padded,
// KT=512. out[img][col] += sum_rows relu(acc + bias) / 512 (atomic).
__global__ __launch_bounds__(256, 2) void k_sage128_pool(
    const ushort_t* __restrict__ Ab, const ushort_t* __restrict__ WT,
    const float* __restrict__ bias, float* __restrict__ out) {
  __shared__ __align__(16) char smem[16384];
  ushort_t* As = (ushort_t*)smem;            // [128][32]
  ushort_t* Bs = (ushort_t*)(smem + 8192);   // [128][32]
  __shared__ float Ps[2][128];

  const int t    = threadIdx.x;
  const int lane = t & 63;
  const int w    = t >> 6;
  const int l15  = lane & 15, lq = lane >> 4;
  const int rowStart = blockIdx.y * 128;
  const int colStart = blockIdx.x * 128;
  const int mrow = (w >> 1) * 64;
  const int ncol = (w & 1) * 64;
  const int KT = 512;

  const int rA0 = t >> 2, rA1 = rA0 + 64;
  const int g   = t & 3;
  const int gsA0 = g ^ (rA0 & 3), gsA1 = g ^ (rA1 & 3);
  const ushort_t* gA0 = Ab + (size_t)(rowStart + rA0) * KT + gsA0 * 8;
  const ushort_t* gA1 = Ab + (size_t)(rowStart + rA1) * KT + gsA1 * 8;
  const ushort_t* gB0 = WT + (size_t)(colStart + rA0) * KT + gsA0 * 8;
  const ushort_t* gB1 = WT + (size_t)(colStart + rA1) * KT + gsA1 * 8;
  ushort_t* lA0 = As + w * 512;
  ushort_t* lA1 = As + 2048 + w * 512;
  ushort_t* lB0 = Bs + w * 512;
  ushort_t* lB1 = Bs + 2048 + w * 512;

  const int pg = (lq ^ (l15 & 3)) * 8;
  int aoff[4], boff[4];
#pragma unroll
  for (int ti = 0; ti < 4; ++ti) aoff[ti] = (mrow + ti * 16 + l15) * 32 + pg;
#pragma unroll
  for (int tj = 0; tj < 4; ++tj) boff[tj] = (ncol + tj * 16 + l15) * 32 + pg;

  f32x4 c00 = {}, c01 = {}, c02 = {}, c03 = {};
  f32x4 c10 = {}, c11 = {}, c12 = {}, c13 = {};
  f32x4 c20 = {}, c21 = {}, c22 = {}, c23 = {};
  f32x4 c30 = {}, c31 = {}, c32 = {}, c33 = {};

#pragma unroll 1
  for (int kt = 0; kt < 16; ++kt) {
    const int k0 = kt * 32;
    ASYNC16(gA0 + k0, lA0);
    ASYNC16(gA1 + k0, lA1);
    ASYNC16(gB0 + k0, lB0);
    ASYNC16(gB1 + k0, lB1);
    __syncthreads();
    bf16x8 a0 = *(const bf16x8*)(As + aoff[0]);
    bf16x8 a1 = *(const bf16x8*)(As + aoff[1]);
    bf16x8 a2 = *(const bf16x8*)(As + aoff[2]);
    bf16x8 a3 = *(const bf16x8*)(As + aoff[3]);
    bf16x8 b0 = *(const bf16x8*)(Bs + boff[0]);
    bf16x8 b1 = *(const bf16x8*)(Bs + boff[1]);
    bf16x8 b2 = *(const bf16x8*)(Bs + boff[2]);
    bf16x8 b3 = *(const bf16x8*)(Bs + boff[3]);
    c00 = __builtin_amdgcn_mfma_f32_16x16x32_bf16(a0, b0, c00, 0, 0, 0);
    c01 = __builtin_amdgcn_mfma_f32_16x16x32_bf16(a0, b1, c01, 0, 0, 0);
    c02 = __builtin_amdgcn_mfma_f32_16x16x32_bf16(a0, b2, c02, 0, 0, 0);
    c03 = __builtin_amdgcn_mfma_f32_16x16x32_bf16(a0, b3, c03, 0, 0, 0);
    c10 = __builtin_amdgcn_mfma_f32_16x16x32_bf16(a1, b0, c10, 0, 0, 0);
    c11 = __builtin_amdgcn_mfma_f32_16x16x32_bf16(a1, b1, c11, 0, 0, 0);
    c12 = __builtin_amdgcn_mfma_f32_16x16x32_bf16(a1, b2, c12, 0, 0, 0);
    c13 = __builtin_amdgcn_mfma_f32_16x16x32_bf16(a1, b3, c13, 0, 0, 0);
    c20 = __builtin_amdgcn_mfma_f32_16x16x32_bf16(a2, b0, c20, 0, 0, 0);
    c21 = __builtin_amdgcn_mfma_f32_16x16x32_bf16(a2, b1, c21, 0, 0, 0);
    c22 = __builtin_amdgcn_mfma_f32_16x16x32_bf16(a2, b2, c22, 0, 0, 0);
    c23 = __builtin_amdgcn_mfma_f32_16x16x32_bf16(a2, b3, c23, 0, 0, 0);
    c30 = __builtin_amdgcn_mfma_f32_16x16x32_bf16(a3, b0, c30, 0, 0, 0);
    c31 = __builtin_amdgcn_mfma_f32_16x16x32_bf16(a3, b1, c31, 0, 0, 0);
    c32 = __builtin_amdgcn_mfma_f32_16x16x32_bf16(a3, b2, c32, 0, 0, 0);
    c33 = __builtin_amdgcn_mfma_f32_16x16x32_bf16(a3, b3, c33, 0, 0, 0);
    __syncthreads();
  }

#define P_ACC(CV)                                                            \
  (fmaxf((CV).x + bv_, 0.f) + fmaxf((CV).y + bv_, 0.f) +                     \
   fmaxf((CV).z + bv_, 0.f) + fmaxf((CV).w + bv_, 0.f))

#define POOL_COL(TJ, C0, C1, C2, C3)                                         \
  do {                                                                       \
    int col_ = colStart + ncol + (TJ) * 16 + l15;                            \
    float bv_ = (col_ < NCLS) ? bias[col_] : 0.f;                            \
    float s_ = P_ACC(C0) + P_ACC(C1) + P_ACC(C2) + P_ACC(C3);                \
    s_ += __shfl_xor(s_, 16);                                                \
    s_ += __shfl_xor(s_, 32);                                                \
    if (lq == 0) Ps[w >> 1][ncol + (TJ) * 16 + l15] = s_;                    \
  } while (0)

  POOL_COL(0, c00, c10, c20, c30);
  POOL_COL(1, c01, c11, c21, c31);
  POOL_COL(2, c02, c12, c22, c32);
  POOL_COL(3, c03, c13, c23, c33);

  __syncthreads();
  if (t < 128) {
    int col = colStart + t;
    if (col < NCLS) {
      float s = Ps[0][t] + Ps[1][t];
      int img = rowStart / NPP;
      atomicAdd(out + (size_t)img * NCLS + col, s * (1.0f / NPP));
    }
  }
}

// ---------------------------------------------------------------------------
extern "C" void kernel_launch(void* const* d_in, const int* in_sizes, int n_in,
                              void* d_out, int out_size, void* d_ws,
                              size_t ws_size, hipStream_t stream) {
  const float* x    = (const float*)d_in[0];
  const float* w_l0 = (const float*)d_in[1];
  const float* b_l0 = (const float*)d_in[2];
  const float* w_r0 = (const float*)d_in[3];
  const float* w_l1 = (const float*)d_in[4];
  const float* b_l1 = (const float*)d_in[5];
  const float* w_r1 = (const float*)d_in[6];
  const float* w_l2 = (const float*)d_in[7];
  const float* b_l2 = (const float*)d_in[8];
  const float* w_r2 = (const float*)d_in[9];
  float* out = (float*)d_out;

  char* ws = (char*)d_ws;
  // phase-1: sq 32KB | idx 288KB | cand_v 18MB | cand_i(u16) 9MB | xs 6MB
  // phase-2 (overlaps dead cand/xs region, all written after k_reduce_topk):
  //   WT0 384KB | WT1 256KB | WT2 1MB | Ab0 6MB | Ab1 8MB | Ab2 8MB
  float*    sq     = (float*)(ws);
  int*      idx    = (int*)(ws + 32768);
  float*    cand_v = (float*)(ws + 327680);
  ushort_t* cand_i = (ushort_t*)(ws + 19202048);
  ushort_t* xs     = (ushort_t*)(ws + 28639232);
  ushort_t* WT0    = (ushort_t*)(ws + 327680);
  ushort_t* WT1    = (ushort_t*)(ws + 720896);
  ushort_t* WT2    = (ushort_t*)(ws + 983040);
  ushort_t* Ab0    = (ushort_t*)(ws + 2031616);
  ushort_t* Ab1    = (ushort_t*)(ws + 8323072);
  ushort_t* Ab2    = (ushort_t*)(ws + 16711680);

  // ---- kNN graph
  k_norms<<<2048, 256, 0, stream>>>(x, sq);
  k_split<<<(NN * FEAT) / 256, 256, 0, stream>>>(x, xs);
  k_dist_topk<<<dim3(64, 64), 256, 0, stream>>>(xs, sq, cand_v, cand_i);
  k_reduce_topk<<<2048, 256, 0, stream>>>(cand_v, cand_i, idx);

  // ---- layers (bf16 MFMA)
  k_cast_w<<<2944, 256, 0, stream>>>(w_l0, w_r0, w_l1, w_r1, w_l2, w_r2,
                                     WT0, WT1, WT2);
  k_zero<<<(NIMG * NCLS + 255) / 256, 256, 0, stream>>>(out, NIMG * NCLS);
  k_gather_l0<<<2048, 256, 0, stream>>>(x, idx, Ab0);
  k_sage64<<<dim3(4, 64), 256, 0, stream>>>(Ab0, WT0, b_l0, Ab1 + 256, 384);
  k_gather_h<<<2048, 256, 0, stream>>>(Ab1 + 256, idx, Ab1);
  k_sage64<<<dim3(4, 64), 256, 0, stream>>>(Ab1, WT1, b_l1, Ab2 + 256, 512);
  k_gather_h<<<2048, 256, 0, stream>>>(Ab2 + 256, idx, Ab2);
  k_sage128_pool<<<dim3(8, 64), 256, 0, stream>>>(Ab2, WT2, b_l2, out);
}

// Round 5
// 236.142 us; speedup vs baseline: 6.0343x; 1.3232x over previous
//
#include <hip/hip_runtime.h>

#define NN   8192
#define FEAT 192
#define HID  256
#define NCLS 1000
#define KNN  9
#define NPP  512          // nodes per image (8192 / 16)
#define NIMG 16
#define KSPL 384          // split-bf16 K (hi|lo concatenated)

typedef unsigned short ushort_t;
typedef unsigned int uint_t;
typedef __attribute__((ext_vector_type(8))) __bf16 bf16x8;
typedef __attribute__((ext_vector_type(4))) float f32x4;

#define ASYNC16(gptr, lptr)                                                  \
  __builtin_amdgcn_global_load_lds(                                          \
      (const __attribute__((address_space(1))) void*)(gptr),                 \
      (__attribute__((address_space(3))) void*)(lptr), 16, 0, 0)

// ---------------------------------------------------------------------------
__device__ __forceinline__ ushort_t f2bf_rne(float f) {
  unsigned u = __float_as_uint(f);
  u += 0x7FFF + ((u >> 16) & 1);          // round-to-nearest-even
  return (ushort_t)(u >> 16);
}
__device__ __forceinline__ float bf2f(ushort_t u) {
  return __uint_as_float((unsigned)u << 16);
}

// sortable-uint transform of float dist, top 19 bits kept, col13 in low bits.
// Monotone: smaller float -> smaller key; equal quantized dist -> smaller col
// wins (matches lax.top_k earlier-index tie rule).
__device__ __forceinline__ uint_t packkey(float f, int col) {
  uint_t b = __float_as_uint(f);
  uint_t m = (uint_t)((int)b >> 31) | 0x80000000u;
  uint_t u = b ^ m;
  return (u & 0xFFFFE000u) | (uint_t)col;
}

// branchless keep-9-smallest: one bubble pass through ascending-sorted tk[].
__device__ __forceinline__ void bubble9(uint_t (&tk)[KNN], uint_t k) {
#pragma unroll
  for (int p = 0; p < KNN; ++p) {
    uint_t lo = min(tk[p], k);
    k = max(tk[p], k);
    tk[p] = lo;
  }
}

// ---------------------------------------------------------------------------
__global__ __launch_bounds__(256) void k_norms(const float* __restrict__ x,
                                               float* __restrict__ sq) {
  int wid  = (blockIdx.x * 256 + threadIdx.x) >> 6;
  int lane = threadIdx.x & 63;
  if (wid >= NN) return;
  const float* row = x + (size_t)wid * FEAT;
  float s = 0.f;
  for (int f = lane; f < FEAT; f += 64) { float v = row[f]; s += v * v; }
#pragma unroll
  for (int off = 32; off > 0; off >>= 1) s += __shfl_down(s, off);
  if (lane == 0) sq[wid] = s;
}

// ---------------------------------------------------------------------------
// split-bf16: xs[i][0..191] = bf16(x), xs[i][192..383] = bf16(x - hi)
__global__ __launch_bounds__(256) void k_split(const float* __restrict__ x,
                                               ushort_t* __restrict__ xs) {
  int i = blockIdx.x * 256 + threadIdx.x;
  if (i >= NN * FEAT) return;
  int r = i / FEAT, c = i - r * FEAT;
  float v = x[i];
  ushort_t h = f2bf_rne(v);
  float hf = bf2f(h);
  ushort_t l = f2bf_rne(v - hf);
  xs[(size_t)r * KSPL + c]        = h;
  xs[(size_t)r * KSPL + FEAT + c] = l;
}

// ---------------------------------------------------------------------------
// MFMA distance + per-colblock top-9, packed-u32 selection.
// 128x128 tile, K=384 bf16 (hi|lo split). Epilogue: per-wave [64][19] u32
// LDS scratch (no block syncs in scan), 18-op bubble per candidate.
__global__ __launch_bounds__(256, 3) void k_dist_topk(
    const ushort_t* __restrict__ xs, const float* __restrict__ sq,
    uint_t* __restrict__ cand) {
  __shared__ __align__(16) char smem[24576];
  ushort_t* As = (ushort_t*)smem;            // [128][32] (granule-swizzled)
  ushort_t* Bs = (ushort_t*)(smem + 8192);
  uint_t*   Ms = (uint_t*)(smem + 19456);    // [128][10] merge buf

  const int t    = threadIdx.x;
  const int lane = t & 63;
  const int w    = t >> 6;
  const int l15  = lane & 15, lq = lane >> 4;
  const int rowStart = blockIdx.y * 128;
  const int colStart = blockIdx.x * 128;
  const int mrow = (w >> 1) * 64;            // wave's row quadrant
  const int ncol = (w & 1) * 64;             // wave's col quadrant

  const int m0 = w * 128 + lane;             // q=0 chunk; q=1 is m0+64
  const int r0 = m0 >> 2, r1 = r0 + 16;
  const int g0 = m0 & 3;
  const int gs0 = g0 ^ (r0 & 3);
  const int gs1 = g0 ^ (r1 & 3);
  const ushort_t* gA0 = xs + (size_t)(rowStart + r0) * KSPL + gs0 * 8;
  const ushort_t* gA1 = xs + (size_t)(rowStart + r1) * KSPL + gs1 * 8;
  const ushort_t* gB0 = xs + (size_t)(colStart + r0) * KSPL + gs0 * 8;
  const ushort_t* gB1 = xs + (size_t)(colStart + r1) * KSPL + gs1 * 8;
  ushort_t* lA = As + w * 1024;              // + q*512 elements
  ushort_t* lB = Bs + w * 1024;

  const int pg = (lq ^ (l15 & 3)) * 8;
  int aoff[4], boff[4];
#pragma unroll
  for (int ti = 0; ti < 4; ++ti) aoff[ti] = (mrow + ti * 16 + l15) * 32 + pg;
#pragma unroll
  for (int tj = 0; tj < 4; ++tj) boff[tj] = (ncol + tj * 16 + l15) * 32 + pg;

  f32x4 c00 = {}, c01 = {}, c02 = {}, c03 = {};
  f32x4 c10 = {}, c11 = {}, c12 = {}, c13 = {};
  f32x4 c20 = {}, c21 = {}, c22 = {}, c23 = {};
  f32x4 c30 = {}, c31 = {}, c32 = {}, c33 = {};

#pragma unroll 1
  for (int kt = 0; kt < 12; ++kt) {
    const int k0 = kt * 32;
    ASYNC16(gA0 + k0, lA);
    ASYNC16(gA1 + k0, lA + 512);
    ASYNC16(gB0 + k0, lB);
    ASYNC16(gB1 + k0, lB + 512);
    __syncthreads();
    bf16x8 a0 = *(const bf16x8*)(As + aoff[0]);
    bf16x8 a1 = *(const bf16x8*)(As + aoff[1]);
    bf16x8 a2 = *(const bf16x8*)(As + aoff[2]);
    bf16x8 a3 = *(const bf16x8*)(As + aoff[3]);
    bf16x8 b0 = *(const bf16x8*)(Bs + boff[0]);
    bf16x8 b1 = *(const bf16x8*)(Bs + boff[1]);
    bf16x8 b2 = *(const bf16x8*)(Bs + boff[2]);
    bf16x8 b3 = *(const bf16x8*)(Bs + boff[3]);
    c00 = __builtin_amdgcn_mfma_f32_16x16x32_bf16(a0, b0, c00, 0, 0, 0);
    c01 = __builtin_amdgcn_mfma_f32_16x16x32_bf16(a0, b1, c01, 0, 0, 0);
    c02 = __builtin_amdgcn_mfma_f32_16x16x32_bf16(a0, b2, c02, 0, 0, 0);
    c03 = __builtin_amdgcn_mfma_f32_16x16x32_bf16(a0, b3, c03, 0, 0, 0);
    c10 = __builtin_amdgcn_mfma_f32_16x16x32_bf16(a1, b0, c10, 0, 0, 0);
    c11 = __builtin_amdgcn_mfma_f32_16x16x32_bf16(a1, b1, c11, 0, 0, 0);
    c12 = __builtin_amdgcn_mfma_f32_16x16x32_bf16(a1, b2, c12, 0, 0, 0);
    c13 = __builtin_amdgcn_mfma_f32_16x16x32_bf16(a1, b3, c13, 0, 0, 0);
    c20 = __builtin_amdgcn_mfma_f32_16x16x32_bf16(a2, b0, c20, 0, 0, 0);
    c21 = __builtin_amdgcn_mfma_f32_16x16x32_bf16(a2, b1, c21, 0, 0, 0);
    c22 = __builtin_amdgcn_mfma_f32_16x16x32_bf16(a2, b2, c22, 0, 0, 0);
    c23 = __builtin_amdgcn_mfma_f32_16x16x32_bf16(a2, b3, c23, 0, 0, 0);
    c30 = __builtin_amdgcn_mfma_f32_16x16x32_bf16(a3, b0, c30, 0, 0, 0);
    c31 = __builtin_amdgcn_mfma_f32_16x16x32_bf16(a3, b1, c31, 0, 0, 0);
    c32 = __builtin_amdgcn_mfma_f32_16x16x32_bf16(a3, b2, c32, 0, 0, 0);
    c33 = __builtin_amdgcn_mfma_f32_16x16x32_bf16(a3, b3, c33, 0, 0, 0);
    __syncthreads();                         // all waves past K-loop
  }

  // ---- epilogue: key = pack(sq[j] - 2*dot, col); per-row top-9 (packed)
  uint_t tk[KNN];
#pragma unroll
  for (int n = 0; n < KNN; ++n) tk[n] = 0xFFFFFFFFu;

  uint_t* Ew = (uint_t*)smem + w * (64 * 19);   // per-wave private scratch

#define EPI_ROW(TI, CV)                                                      \
  do {                                                                       \
    f32x4 v_ = (CV);                                                         \
    Ew[((TI) * 16 + lq * 4 + 0) * 19 + l15] =                                \
        packkey(fmaf(-2.0f, v_.x, sqv), mycol);                              \
    Ew[((TI) * 16 + lq * 4 + 1) * 19 + l15] =                                \
        packkey(fmaf(-2.0f, v_.y, sqv), mycol);                              \
    Ew[((TI) * 16 + lq * 4 + 2) * 19 + l15] =                                \
        packkey(fmaf(-2.0f, v_.z, sqv), mycol);                              \
    Ew[((TI) * 16 + lq * 4 + 3) * 19 + l15] =                                \
        packkey(fmaf(-2.0f, v_.w, sqv), mycol);                              \
  } while (0)

#define EPI_TILE(TJ, C0, C1, C2, C3)                                         \
  do {                                                                       \
    int mycol = colStart + ncol + (TJ) * 16 + l15;                           \
    float sqv = sq[mycol];                                                   \
    EPI_ROW(0, C0); EPI_ROW(1, C1); EPI_ROW(2, C2); EPI_ROW(3, C3);          \
    _Pragma("unroll")                                                        \
    for (int c = 0; c < 16; ++c) bubble9(tk, Ew[lane * 19 + c]);             \
  } while (0)

  EPI_TILE(0, c00, c10, c20, c30);
  EPI_TILE(1, c01, c11, c21, c31);
  EPI_TILE(2, c02, c12, c22, c32);
  EPI_TILE(3, c03, c13, c23, c33);

  // merge the two waves sharing each row half, write candidates
  __syncthreads();
  if (w & 1) {
#pragma unroll
    for (int n = 0; n < KNN; ++n) Ms[(mrow + lane) * 10 + n] = tk[n];
  }
  __syncthreads();
  if (!(w & 1)) {
#pragma unroll
    for (int n = 0; n < KNN; ++n) bubble9(tk, Ms[(mrow + lane) * 10 + n]);
    size_t base = (((size_t)(rowStart + mrow + lane)) * 64 + blockIdx.x) * KNN;
#pragma unroll
    for (int n = 0; n < KNN; ++n) cand[base + n] = tk[n];
  }
}

// ---------------------------------------------------------------------------
// one wave per row: merge 64 colblocks x 9 = 576 packed candidates -> idx
__global__ __launch_bounds__(256) void k_reduce_topk(
    const uint_t* __restrict__ cand, int* __restrict__ idx) {
  int wid  = (blockIdx.x * 256 + threadIdx.x) >> 6;
  int lane = threadIdx.x & 63;
  if (wid >= NN) return;
  const uint_t* cv = cand + (size_t)wid * 576;
  uint_t tk[KNN];
#pragma unroll
  for (int n = 0; n < KNN; ++n) tk[n] = 0xFFFFFFFFu;
#pragma unroll
  for (int m = 0; m < KNN; ++m) bubble9(tk, cv[lane + 64 * m]);

  for (int r = 0; r < KNN; ++r) {
    uint_t bm = tk[0];                       // lane-local min (sorted)
#pragma unroll
    for (int off = 32; off > 0; off >>= 1)
      bm = min(bm, (uint_t)__shfl_xor((unsigned int)bm, off));
    if (tk[0] == bm) {                       // keys unique: exactly one lane
#pragma unroll
      for (int p = 0; p < KNN - 1; ++p) tk[p] = tk[p + 1];
      tk[KNN - 1] = 0xFFFFFFFFu;
    }
    if (lane == 0) idx[wid * KNN + r] = (int)(bm & 0x1FFFu);
  }
}

// ---------------------------------------------------------------------------
// WT_l[n][k] = [w_l ; w_r]^T in bf16; L2 padded to 1024 rows (zero fill).
__global__ __launch_bounds__(256) void k_cast_w(
    const float* __restrict__ w_l0, const float* __restrict__ w_r0,
    const float* __restrict__ w_l1, const float* __restrict__ w_r1,
    const float* __restrict__ w_l2, const float* __restrict__ w_r2,
    ushort_t* __restrict__ WT0, ushort_t* __restrict__ WT1,
    ushort_t* __restrict__ WT2) {
  int i = blockIdx.x * 256 + threadIdx.x;
  if (i < 98304) {                               // 256 x 384
    int n = i / 384, k = i - n * 384;
    float v = (k < 192) ? w_l0[k * 256 + n] : w_r0[(k - 192) * 256 + n];
    WT0[i] = f2bf_rne(v);
  } else if (i < 98304 + 131072) {               // 256 x 512
    int j = i - 98304;
    int n = j / 512, k = j - n * 512;
    float v = (k < 256) ? w_l1[k * 256 + n] : w_r1[(k - 256) * 256 + n];
    WT1[j] = f2bf_rne(v);
  } else {                                       // 1024 x 512 (rows>=1000: 0)
    int j = i - (98304 + 131072);
    int n = j / 512, k = j - n * 512;
    float v = 0.f;
    if (n < NCLS)
      v = (k < 256) ? w_l2[k * NCLS + n] : w_r2[(k - 256) * NCLS + n];
    WT2[j] = f2bf_rne(v);
  }
}

// ---------------------------------------------------------------------------
// layer-0 input build: Ab0[row][0..191] = bf16(mean9 x), [192..383] = bf16(x)
__global__ __launch_bounds__(256) void k_gather_l0(
    const float* __restrict__ x, const int* __restrict__ idx,
    ushort_t* __restrict__ Ab0) {
  int wid  = (blockIdx.x * 256 + threadIdx.x) >> 6;
  int lane = threadIdx.x & 63;
  if (wid >= NN) return;
  int nb[KNN];
#pragma unroll
  for (int n = 0; n < KNN; ++n) nb[n] = idx[wid * KNN + n];
#pragma unroll
  for (int f = lane; f < FEAT; f += 64) {
    float s = 0.f;
#pragma unroll
    for (int n = 0; n < KNN; ++n) s += x[(size_t)nb[n] * FEAT + f];
    Ab0[(size_t)wid * KSPL + f]        = f2bf_rne(s * (1.0f / KNN));
    Ab0[(size_t)wid * KSPL + FEAT + f] = f2bf_rne(x[(size_t)wid * FEAT + f]);
  }
}

// layer-1/2 agg build: hsrc = Ab+256 (bf16, row stride 512); adst = Ab cols 0..255
__global__ __launch_bounds__(256) void k_gather_h(
    const ushort_t* __restrict__ hsrc, const int* __restrict__ idx,
    ushort_t* __restrict__ adst) {
  int wid  = (blockIdx.x * 256 + threadIdx.x) >> 6;
  int lane = threadIdx.x & 63;
  if (wid >= NN) return;
  int nb[KNN];
#pragma unroll
  for (int n = 0; n < KNN; ++n) nb[n] = idx[wid * KNN + n];
#pragma unroll
  for (int f = lane; f < HID; f += 64) {
    float s = 0.f;
#pragma unroll
    for (int n = 0; n < KNN; ++n) s += bf2f(hsrc[(size_t)nb[n] * 512 + f]);
    adst[(size_t)wid * 512 + f] = f2bf_rne(s * (1.0f / KNN));
  }
}

// ---------------------------------------------------------------------------
__global__ void k_zero(float* __restrict__ out, int n) {
  int i = blockIdx.x * 256 + threadIdx.x;
  if (i < n) out[i] = 0.f;
}

// ---------------------------------------------------------------------------
// bf16 MFMA SAGE layer, BM=128 BN=64, N=256. hdst = next-layer Ab + 256.
__global__ __launch_bounds__(256, 4) void k_sage64(
    const ushort_t* __restrict__ Ab, const ushort_t* __restrict__ WT,
    const float* __restrict__ bias, ushort_t* __restrict__ hdst, int KT) {
  __shared__ __align__(16) char smem[12288];
  ushort_t* As = (ushort_t*)smem;            // [128][32]
  ushort_t* Bs = (ushort_t*)(smem + 8192);   // [64][32]

  const int t    = threadIdx.x;
  const int lane = t & 63;
  const int w    = t >> 6;
  const int l15  = lane & 15, lq = lane >> 4;
  const int rowStart = blockIdx.y * 128;
  const int colStart = blockIdx.x * 64;
  const int mrow = (w >> 1) * 64;
  const int ncol = (w & 1) * 32;

  const int rA0 = t >> 2, rA1 = rA0 + 64;
  const int g   = t & 3;
  const int gsA0 = g ^ (rA0 & 3), gsA1 = g ^ (rA1 & 3);
  const ushort_t* gA0 = Ab + (size_t)(rowStart + rA0) * KT + gsA0 * 8;
  const ushort_t* gA1 = Ab + (size_t)(rowStart + rA1) * KT + gsA1 * 8;
  const ushort_t* gB0 = WT + (size_t)(colStart + rA0) * KT + gsA0 * 8;
  ushort_t* lA0 = As + w * 512;
  ushort_t* lA1 = As + 2048 + w * 512;
  ushort_t* lB0 = Bs + w * 512;

  const int pg = (lq ^ (l15 & 3)) * 8;
  int aoff[4], boff[2];
#pragma unroll
  for (int ti = 0; ti < 4; ++ti) aoff[ti] = (mrow + ti * 16 + l15) * 32 + pg;
#pragma unroll
  for (int tj = 0; tj < 2; ++tj) boff[tj] = (ncol + tj * 16 + l15) * 32 + pg;

  f32x4 c00 = {}, c01 = {};
  f32x4 c10 = {}, c11 = {};
  f32x4 c20 = {}, c21 = {};
  f32x4 c30 = {}, c31 = {};

  const int nkt = KT >> 5;
#pragma unroll 1
  for (int kt = 0; kt < nkt; ++kt) {
    const int k0 = kt * 32;
    ASYNC16(gA0 + k0, lA0);
    ASYNC16(gA1 + k0, lA1);
    ASYNC16(gB0 + k0, lB0);
    __syncthreads();
    bf16x8 a0 = *(const bf16x8*)(As + aoff[0]);
    bf16x8 a1 = *(const bf16x8*)(As + aoff[1]);
    bf16x8 a2 = *(const bf16x8*)(As + aoff[2]);
    bf16x8 a3 = *(const bf16x8*)(As + aoff[3]);
    bf16x8 b0 = *(const bf16x8*)(Bs + boff[0]);
    bf16x8 b1 = *(const bf16x8*)(Bs + boff[1]);
    c00 = __builtin_amdgcn_mfma_f32_16x16x32_bf16(a0, b0, c00, 0, 0, 0);
    c01 = __builtin_amdgcn_mfma_f32_16x16x32_bf16(a0, b1, c01, 0, 0, 0);
    c10 = __builtin_amdgcn_mfma_f32_16x16x32_bf16(a1, b0, c10, 0, 0, 0);
    c11 = __builtin_amdgcn_mfma_f32_16x16x32_bf16(a1, b1, c11, 0, 0, 0);
    c20 = __builtin_amdgcn_mfma_f32_16x16x32_bf16(a2, b0, c20, 0, 0, 0);
    c21 = __builtin_amdgcn_mfma_f32_16x16x32_bf16(a2, b1, c21, 0, 0, 0);
    c30 = __builtin_amdgcn_mfma_f32_16x16x32_bf16(a3, b0, c30, 0, 0, 0);
    c31 = __builtin_amdgcn_mfma_f32_16x16x32_bf16(a3, b1, c31, 0, 0, 0);
    __syncthreads();
  }

  const float bv0 = bias[colStart + ncol + l15];
  const float bv1 = bias[colStart + ncol + 16 + l15];

#define S64_STORE(TI, TJ, CV, BV)                                            \
  do {                                                                       \
    f32x4 v_ = (CV);                                                         \
    int col_ = colStart + ncol + (TJ) * 16 + l15;                            \
    size_t rb_ = (size_t)(rowStart + mrow + (TI) * 16 + lq * 4);             \
    hdst[(rb_ + 0) * 512 + col_] = f2bf_rne(fmaxf(v_.x + (BV), 0.f));        \
    hdst[(rb_ + 1) * 512 + col_] = f2bf_rne(fmaxf(v_.y + (BV), 0.f));        \
    hdst[(rb_ + 2) * 512 + col_] = f2bf_rne(fmaxf(v_.z + (BV), 0.f));        \
    hdst[(rb_ + 3) * 512 + col_] = f2bf_rne(fmaxf(v_.w + (BV), 0.f));        \
  } while (0)

  S64_STORE(0, 0, c00, bv0); S64_STORE(0, 1, c01, bv1);
  S64_STORE(1, 0, c10, bv0); S64_STORE(1, 1, c11, bv1);
  S64_STORE(2, 0, c20, bv0); S64_STORE(2, 1, c21, bv1);
  S64_STORE(3, 0, c30, bv0); S64_STORE(3, 1, c31, bv1);
}

// ---------------------------------------------------------------------------
// bf16 MFMA layer-2 + fused global mean pool. BM=128 BN=128, N=1024 padded.
__global__ __launch_bounds__(256, 2) void k_sage128_pool(
    const ushort_t* __restrict__ Ab, const ushort_t* __restrict__ WT,
    const float* __restrict__ bias, float* __restrict__ out) {
  __shared__ __align__(16) char smem[16384];
  ushort_t* As = (ushort_t*)smem;            // [128][32]
  ushort_t* Bs = (ushort_t*)(smem + 8192);   // [128][32]
  __shared__ float Ps[2][128];

  const int t    = threadIdx.x;
  const int lane = t & 63;
  const int w    = t >> 6;
  const int l15  = lane & 15, lq = lane >> 4;
  const int rowStart = blockIdx.y * 128;
  const int colStart = blockIdx.x * 128;
  const int mrow = (w >> 1) * 64;
  const int ncol = (w & 1) * 64;
  const int KT = 512;

  const int rA0 = t >> 2, rA1 = rA0 + 64;
  const int g   = t & 3;
  const int gsA0 = g ^ (rA0 & 3), gsA1 = g ^ (rA1 & 3);
  const ushort_t* gA0 = Ab + (size_t)(rowStart + rA0) * KT + gsA0 * 8;
  const ushort_t* gA1 = Ab + (size_t)(rowStart + rA1) * KT + gsA1 * 8;
  const ushort_t* gB0 = WT + (size_t)(colStart + rA0) * KT + gsA0 * 8;
  const ushort_t* gB1 = WT + (size_t)(colStart + rA1) * KT + gsA1 * 8;
  ushort_t* lA0 = As + w * 512;
  ushort_t* lA1 = As + 2048 + w * 512;
  ushort_t* lB0 = Bs + w * 512;
  ushort_t* lB1 = Bs + 2048 + w * 512;

  const int pg = (lq ^ (l15 & 3)) * 8;
  int aoff[4], boff[4];
#pragma unroll
  for (int ti = 0; ti < 4; ++ti) aoff[ti] = (mrow + ti * 16 + l15) * 32 + pg;
#pragma unroll
  for (int tj = 0; tj < 4; ++tj) boff[tj] = (ncol + tj * 16 + l15) * 32 + pg;

  f32x4 c00 = {}, c01 = {}, c02 = {}, c03 = {};
  f32x4 c10 = {}, c11 = {}, c12 = {}, c13 = {};
  f32x4 c20 = {}, c21 = {}, c22 = {}, c23 = {};
  f32x4 c30 = {}, c31 = {}, c32 = {}, c33 = {};

#pragma unroll 1
  for (int kt = 0; kt < 16; ++kt) {
    const int k0 = kt * 32;
    ASYNC16(gA0 + k0, lA0);
    ASYNC16(gA1 + k0, lA1);
    ASYNC16(gB0 + k0, lB0);
    ASYNC16(gB1 + k0, lB1);
    __syncthreads();
    bf16x8 a0 = *(const bf16x8*)(As + aoff[0]);
    bf16x8 a1 = *(const bf16x8*)(As + aoff[1]);
    bf16x8 a2 = *(const bf16x8*)(As + aoff[2]);
    bf16x8 a3 = *(const bf16x8*)(As + aoff[3]);
    bf16x8 b0 = *(const bf16x8*)(Bs + boff[0]);
    bf16x8 b1 = *(const bf16x8*)(Bs + boff[1]);
    bf16x8 b2 = *(const bf16x8*)(Bs + boff[2]);
    bf16x8 b3 = *(const bf16x8*)(Bs + boff[3]);
    c00 = __builtin_amdgcn_mfma_f32_16x16x32_bf16(a0, b0, c00, 0, 0, 0);
    c01 = __builtin_amdgcn_mfma_f32_16x16x32_bf16(a0, b1, c01, 0, 0, 0);
    c02 = __builtin_amdgcn_mfma_f32_16x16x32_bf16(a0, b2, c02, 0, 0, 0);
    c03 = __builtin_amdgcn_mfma_f32_16x16x32_bf16(a0, b3, c03, 0, 0, 0);
    c10 = __builtin_amdgcn_mfma_f32_16x16x32_bf16(a1, b0, c10, 0, 0, 0);
    c11 = __builtin_amdgcn_mfma_f32_16x16x32_bf16(a1, b1, c11, 0, 0, 0);
    c12 = __builtin_amdgcn_mfma_f32_16x16x32_bf16(a1, b2, c12, 0, 0, 0);
    c13 = __builtin_amdgcn_mfma_f32_16x16x32_bf16(a1, b3, c13, 0, 0, 0);
    c20 = __builtin_amdgcn_mfma_f32_16x16x32_bf16(a2, b0, c20, 0, 0, 0);
    c21 = __builtin_amdgcn_mfma_f32_16x16x32_bf16(a2, b1, c21, 0, 0, 0);
    c22 = __builtin_amdgcn_mfma_f32_16x16x32_bf16(a2, b2, c22, 0, 0, 0);
    c23 = __builtin_amdgcn_mfma_f32_16x16x32_bf16(a2, b3, c23, 0, 0, 0);
    c30 = __builtin_amdgcn_mfma_f32_16x16x32_bf16(a3, b0, c30, 0, 0, 0);
    c31 = __builtin_amdgcn_mfma_f32_16x16x32_bf16(a3, b1, c31, 0, 0, 0);
    c32 = __builtin_amdgcn_mfma_f32_16x16x32_bf16(a3, b2, c32, 0, 0, 0);
    c33 = __builtin_amdgcn_mfma_f32_16x16x32_bf16(a3, b3, c33, 0, 0, 0);
    __syncthreads();
  }

#define P_ACC(CV)                                                            \
  (fmaxf((CV).x + bv_, 0.f) + fmaxf((CV).y + bv_, 0.f) +                     \
   fmaxf((CV).z + bv_, 0.f) + fmaxf((CV).w + bv_, 0.f))

#define POOL_COL(TJ, C0, C1, C2, C3)                                         \
  do {                                                                       \
    int col_ = colStart + ncol + (TJ) * 16 + l15;                            \
    float bv_ = (col_ < NCLS) ? bias[col_] : 0.f;                            \
    float s_ = P_ACC(C0) + P_ACC(C1) + P_ACC(C2) + P_ACC(C3);                \
    s_ += __shfl_xor(s_, 16);                                                \
    s_ += __shfl_xor(s_, 32);                                                \
    if (lq == 0) Ps[w >> 1][ncol + (TJ) * 16 + l15] = s_;                    \
  } while (0)

  POOL_COL(0, c00, c10, c20, c30);
  POOL_COL(1, c01, c11, c21, c31);
  POOL_COL(2, c02, c12, c22, c32);
  POOL_COL(3, c03, c13, c23, c33);

  __syncthreads();
  if (t < 128) {
    int col = colStart + t;
    if (col < NCLS) {
      float s = Ps[0][t] + Ps[1][t];
      int img = rowStart / NPP;
      atomicAdd(out + (size_t)img * NCLS + col, s * (1.0f / NPP));
    }
  }
}

// ---------------------------------------------------------------------------
extern "C" void kernel_launch(void* const* d_in, const int* in_sizes, int n_in,
                              void* d_out, int out_size, void* d_ws,
                              size_t ws_size, hipStream_t stream) {
  const float* x    = (const float*)d_in[0];
  const float* w_l0 = (const float*)d_in[1];
  const float* b_l0 = (const float*)d_in[2];
  const float* w_r0 = (const float*)d_in[3];
  const float* w_l1 = (const float*)d_in[4];
  const float* b_l1 = (const float*)d_in[5];
  const float* w_r1 = (const float*)d_in[6];
  const float* w_l2 = (const float*)d_in[7];
  const float* b_l2 = (const float*)d_in[8];
  const float* w_r2 = (const float*)d_in[9];
  float* out = (float*)d_out;

  char* ws = (char*)d_ws;
  // phase-1: sq 32KB | idx 288KB | cand(u32) 18.9MB | xs 6MB
  // phase-2 (overlaps dead cand region, written after k_reduce_topk):
  //   WT0 384KB | WT1 256KB | WT2 1MB | Ab0 6MB | Ab1 8MB | Ab2 8MB
  float*    sq   = (float*)(ws);
  int*      idx  = (int*)(ws + 32768);
  uint_t*   cand = (uint_t*)(ws + 327680);
  ushort_t* xs   = (ushort_t*)(ws + 28639232);
  ushort_t* WT0  = (ushort_t*)(ws + 327680);
  ushort_t* WT1  = (ushort_t*)(ws + 720896);
  ushort_t* WT2  = (ushort_t*)(ws + 983040);
  ushort_t* Ab0  = (ushort_t*)(ws + 2031616);
  ushort_t* Ab1  = (ushort_t*)(ws + 8323072);
  ushort_t* Ab2  = (ushort_t*)(ws + 16711680);

  // ---- kNN graph
  k_norms<<<2048, 256, 0, stream>>>(x, sq);
  k_split<<<(NN * FEAT) / 256, 256, 0, stream>>>(x, xs);
  k_dist_topk<<<dim3(64, 64), 256, 0, stream>>>(xs, sq, cand);
  k_reduce_topk<<<2048, 256, 0, stream>>>(cand, idx);

  // ---- layers (bf16 MFMA)
  k_cast_w<<<2944, 256, 0, stream>>>(w_l0, w_r0, w_l1, w_r1, w_l2, w_r2,
                                     WT0, WT1, WT2);
  k_zero<<<(NIMG * NCLS + 255) / 256, 256, 0, stream>>>(out, NIMG * NCLS);
  k_gather_l0<<<2048, 256, 0, stream>>>(x, idx, Ab0);
  k_sage64<<<dim3(4, 64), 256, 0, stream>>>(Ab0, WT0, b_l0, Ab1 + 256, 384);
  k_gather_h<<<2048, 256, 0, stream>>>(Ab1 + 256, idx, Ab1);
  k_sage64<<<dim3(4, 64), 256, 0, stream>>>(Ab1, WT1, b_l1, Ab2 + 256, 512);
  k_gather_h<<<2048, 256, 0, stream>>>(Ab2 + 256, idx, Ab2);
  k_sage128_pool<<<dim3(8, 64), 256, 0, stream>>>(Ab2, WT2, b_l2, out);
}

// Round 6
// 224.146 us; speedup vs baseline: 6.3572x; 1.0535x over previous
//
#include <hip/hip_runtime.h>

#define NN   8192
#define FEAT 192
#define HID  256
#define NCLS 1000
#define KNN  9
#define NPP  512          // nodes per image (8192 / 16)
#define NIMG 16
#define KSPL 384          // split-bf16 K (hi|lo concatenated)

typedef unsigned short ushort_t;
typedef unsigned int uint_t;
typedef __attribute__((ext_vector_type(8))) __bf16 bf16x8;
typedef __attribute__((ext_vector_type(4))) float f32x4;

#define ASYNC16(gptr, lptr)                                                  \
  __builtin_amdgcn_global_load_lds(                                          \
      (const __attribute__((address_space(1))) void*)(gptr),                 \
      (__attribute__((address_space(3))) void*)(lptr), 16, 0, 0)

// ---------------------------------------------------------------------------
__device__ __forceinline__ ushort_t f2bf_rne(float f) {
  unsigned u = __float_as_uint(f);
  u += 0x7FFF + ((u >> 16) & 1);          // round-to-nearest-even
  return (ushort_t)(u >> 16);
}
__device__ __forceinline__ float bf2f(ushort_t u) {
  return __uint_as_float((unsigned)u << 16);
}

// sortable-uint transform of float dist, top 19 bits kept, col13 in low bits.
__device__ __forceinline__ uint_t packkey(float f, int col) {
  uint_t b = __float_as_uint(f);
  uint_t m = (uint_t)((int)b >> 31) | 0x80000000u;
  uint_t u = b ^ m;
  return (u & 0xFFFFE000u) | (uint_t)col;
}

// branchless keep-9-smallest: one bubble pass through ascending-sorted tk[].
__device__ __forceinline__ void bubble9(uint_t (&tk)[KNN], uint_t k) {
#pragma unroll
  for (int p = 0; p < KNN; ++p) {
    uint_t lo = min(tk[p], k);
    k = max(tk[p], k);
    tk[p] = lo;
  }
}

// ---------------------------------------------------------------------------
// fused: row norms + split-bf16 (one pass over x). wave per row.
__global__ __launch_bounds__(256) void k_norms_split(
    const float* __restrict__ x, float* __restrict__ sq,
    ushort_t* __restrict__ xs) {
  int wid  = (blockIdx.x * 256 + threadIdx.x) >> 6;
  int lane = threadIdx.x & 63;
  if (wid >= NN) return;
  const float* row = x + (size_t)wid * FEAT;
  ushort_t* xr = xs + (size_t)wid * KSPL;
  float s = 0.f;
#pragma unroll
  for (int f0 = 0; f0 < FEAT; f0 += 64) {
    int f = f0 + lane;
    float v = row[f];
    s += v * v;
    ushort_t h = f2bf_rne(v);
    ushort_t l = f2bf_rne(v - bf2f(h));
    xr[f]        = h;
    xr[FEAT + f] = l;
  }
#pragma unroll
  for (int off = 32; off > 0; off >>= 1) s += __shfl_down(s, off);
  if (lane == 0) sq[wid] = s;
}

// ---------------------------------------------------------------------------
// MFMA distance + per-colblock top-9, packed-u32 selection.
// R6: __launch_bounds__(256,4) — 120 regs (56 VGPR + 64 AGPR) fits the
// 128/wave budget at 4 blocks/CU; LDS 24576*4 = 96 KB < 160 KB.
__global__ __launch_bounds__(256, 4) void k_dist_topk(
    const ushort_t* __restrict__ xs, const float* __restrict__ sq,
    uint_t* __restrict__ cand) {
  __shared__ __align__(16) char smem[24576];
  ushort_t* As = (ushort_t*)smem;            // [128][32] (granule-swizzled)
  ushort_t* Bs = (ushort_t*)(smem + 8192);
  uint_t*   Ms = (uint_t*)(smem + 19456);    // [128][10] merge buf

  const int t    = threadIdx.x;
  const int lane = t & 63;
  const int w    = t >> 6;
  const int l15  = lane & 15, lq = lane >> 4;
  const int rowStart = blockIdx.y * 128;
  const int colStart = blockIdx.x * 128;
  const int mrow = (w >> 1) * 64;            // wave's row quadrant
  const int ncol = (w & 1) * 64;             // wave's col quadrant

  const int m0 = w * 128 + lane;             // q=0 chunk; q=1 is m0+64
  const int r0 = m0 >> 2, r1 = r0 + 16;
  const int g0 = m0 & 3;
  const int gs0 = g0 ^ (r0 & 3);
  const int gs1 = g0 ^ (r1 & 3);
  const ushort_t* gA0 = xs + (size_t)(rowStart + r0) * KSPL + gs0 * 8;
  const ushort_t* gA1 = xs + (size_t)(rowStart + r1) * KSPL + gs1 * 8;
  const ushort_t* gB0 = xs + (size_t)(colStart + r0) * KSPL + gs0 * 8;
  const ushort_t* gB1 = xs + (size_t)(colStart + r1) * KSPL + gs1 * 8;
  ushort_t* lA = As + w * 1024;              // + q*512 elements
  ushort_t* lB = Bs + w * 1024;

  const int pg = (lq ^ (l15 & 3)) * 8;
  int aoff[4], boff[4];
#pragma unroll
  for (int ti = 0; ti < 4; ++ti) aoff[ti] = (mrow + ti * 16 + l15) * 32 + pg;
#pragma unroll
  for (int tj = 0; tj < 4; ++tj) boff[tj] = (ncol + tj * 16 + l15) * 32 + pg;

  f32x4 c00 = {}, c01 = {}, c02 = {}, c03 = {};
  f32x4 c10 = {}, c11 = {}, c12 = {}, c13 = {};
  f32x4 c20 = {}, c21 = {}, c22 = {}, c23 = {};
  f32x4 c30 = {}, c31 = {}, c32 = {}, c33 = {};

#pragma unroll 1
  for (int kt = 0; kt < 12; ++kt) {
    const int k0 = kt * 32;
    ASYNC16(gA0 + k0, lA);
    ASYNC16(gA1 + k0, lA + 512);
    ASYNC16(gB0 + k0, lB);
    ASYNC16(gB1 + k0, lB + 512);
    __syncthreads();
    bf16x8 a0 = *(const bf16x8*)(As + aoff[0]);
    bf16x8 a1 = *(const bf16x8*)(As + aoff[1]);
    bf16x8 a2 = *(const bf16x8*)(As + aoff[2]);
    bf16x8 a3 = *(const bf16x8*)(As + aoff[3]);
    bf16x8 b0 = *(const bf16x8*)(Bs + boff[0]);
    bf16x8 b1 = *(const bf16x8*)(Bs + boff[1]);
    bf16x8 b2 = *(const bf16x8*)(Bs + boff[2]);
    bf16x8 b3 = *(const bf16x8*)(Bs + boff[3]);
    c00 = __builtin_amdgcn_mfma_f32_16x16x32_bf16(a0, b0, c00, 0, 0, 0);
    c01 = __builtin_amdgcn_mfma_f32_16x16x32_bf16(a0, b1, c01, 0, 0, 0);
    c02 = __builtin_amdgcn_mfma_f32_16x16x32_bf16(a0, b2, c02, 0, 0, 0);
    c03 = __builtin_amdgcn_mfma_f32_16x16x32_bf16(a0, b3, c03, 0, 0, 0);
    c10 = __builtin_amdgcn_mfma_f32_16x16x32_bf16(a1, b0, c10, 0, 0, 0);
    c11 = __builtin_amdgcn_mfma_f32_16x16x32_bf16(a1, b1, c11, 0, 0, 0);
    c12 = __builtin_amdgcn_mfma_f32_16x16x32_bf16(a1, b2, c12, 0, 0, 0);
    c13 = __builtin_amdgcn_mfma_f32_16x16x32_bf16(a1, b3, c13, 0, 0, 0);
    c20 = __builtin_amdgcn_mfma_f32_16x16x32_bf16(a2, b0, c20, 0, 0, 0);
    c21 = __builtin_amdgcn_mfma_f32_16x16x32_bf16(a2, b1, c21, 0, 0, 0);
    c22 = __builtin_amdgcn_mfma_f32_16x16x32_bf16(a2, b2, c22, 0, 0, 0);
    c23 = __builtin_amdgcn_mfma_f32_16x16x32_bf16(a2, b3, c23, 0, 0, 0);
    c30 = __builtin_amdgcn_mfma_f32_16x16x32_bf16(a3, b0, c30, 0, 0, 0);
    c31 = __builtin_amdgcn_mfma_f32_16x16x32_bf16(a3, b1, c31, 0, 0, 0);
    c32 = __builtin_amdgcn_mfma_f32_16x16x32_bf16(a3, b2, c32, 0, 0, 0);
    c33 = __builtin_amdgcn_mfma_f32_16x16x32_bf16(a3, b3, c33, 0, 0, 0);
    __syncthreads();                         // all waves past K-loop
  }

  // ---- epilogue: key = pack(sq[j] - 2*dot, col); per-row top-9 (packed)
  uint_t tk[KNN];
#pragma unroll
  for (int n = 0; n < KNN; ++n) tk[n] = 0xFFFFFFFFu;

  uint_t* Ew = (uint_t*)smem + w * (64 * 19);   // per-wave private scratch

#define EPI_ROW(TI, CV)                                                      \
  do {                                                                       \
    f32x4 v_ = (CV);                                                         \
    Ew[((TI) * 16 + lq * 4 + 0) * 19 + l15] =                                \
        packkey(fmaf(-2.0f, v_.x, sqv), mycol);                              \
    Ew[((TI) * 16 + lq * 4 + 1) * 19 + l15] =                                \
        packkey(fmaf(-2.0f, v_.y, sqv), mycol);                              \
    Ew[((TI) * 16 + lq * 4 + 2) * 19 + l15] =                                \
        packkey(fmaf(-2.0f, v_.z, sqv), mycol);                              \
    Ew[((TI) * 16 + lq * 4 + 3) * 19 + l15] =                                \
        packkey(fmaf(-2.0f, v_.w, sqv), mycol);                              \
  } while (0)

#define EPI_TILE(TJ, C0, C1, C2, C3)                                         \
  do {                                                                       \
    int mycol = colStart + ncol + (TJ) * 16 + l15;                           \
    float sqv = sq[mycol];                                                   \
    EPI_ROW(0, C0); EPI_ROW(1, C1); EPI_ROW(2, C2); EPI_ROW(3, C3);          \
    _Pragma("unroll")                                                        \
    for (int c = 0; c < 16; ++c) bubble9(tk, Ew[lane * 19 + c]);             \
  } while (0)

  EPI_TILE(0, c00, c10, c20, c30);
  EPI_TILE(1, c01, c11, c21, c31);
  EPI_TILE(2, c02, c12, c22, c32);
  EPI_TILE(3, c03, c13, c23, c33);

  // merge the two waves sharing each row half, write candidates
  __syncthreads();
  if (w & 1) {
#pragma unroll
    for (int n = 0; n < KNN; ++n) Ms[(mrow + lane) * 10 + n] = tk[n];
  }
  __syncthreads();
  if (!(w & 1)) {
#pragma unroll
    for (int n = 0; n < KNN; ++n) bubble9(tk, Ms[(mrow + lane) * 10 + n]);
    size_t base = (((size_t)(rowStart + mrow + lane)) * 64 + blockIdx.x) * KNN;
#pragma unroll
    for (int n = 0; n < KNN; ++n) cand[base + n] = tk[n];
  }
}

// ---------------------------------------------------------------------------
// fused: merge 64x9 packed candidates -> 9 neighbor idx -> layer-0 gather.
// One wave per row; extracted neighbors stay in registers for the gather.
__global__ __launch_bounds__(256) void k_reduce_gather(
    const uint_t* __restrict__ cand, const float* __restrict__ x,
    int* __restrict__ idx, ushort_t* __restrict__ Ab0) {
  int wid  = (blockIdx.x * 256 + threadIdx.x) >> 6;
  int lane = threadIdx.x & 63;
  if (wid >= NN) return;
  const uint_t* cv = cand + (size_t)wid * 576;
  uint_t tk[KNN];
#pragma unroll
  for (int n = 0; n < KNN; ++n) tk[n] = 0xFFFFFFFFu;
#pragma unroll
  for (int m = 0; m < KNN; ++m) bubble9(tk, cv[lane + 64 * m]);

  int nb[KNN];
  for (int r = 0; r < KNN; ++r) {
    uint_t bm = tk[0];                       // lane-local min (sorted)
#pragma unroll
    for (int off = 32; off > 0; off >>= 1)
      bm = min(bm, (uint_t)__shfl_xor((unsigned int)bm, off));
    if (tk[0] == bm) {                       // keys unique: exactly one lane
#pragma unroll
      for (int p = 0; p < KNN - 1; ++p) tk[p] = tk[p + 1];
      tk[KNN - 1] = 0xFFFFFFFFu;
    }
    nb[r] = (int)(bm & 0x1FFFu);             // all lanes keep the winner
    if (lane == 0) idx[wid * KNN + r] = nb[r];
  }

  // layer-0 input build: Ab0[row][0..191]=bf16(mean9 x), [192..383]=bf16(x)
#pragma unroll
  for (int f0 = 0; f0 < FEAT; f0 += 64) {
    int f = f0 + lane;
    float s = 0.f;
#pragma unroll
    for (int n = 0; n < KNN; ++n) s += x[(size_t)nb[n] * FEAT + f];
    Ab0[(size_t)wid * KSPL + f]        = f2bf_rne(s * (1.0f / KNN));
    Ab0[(size_t)wid * KSPL + FEAT + f] = f2bf_rne(x[(size_t)wid * FEAT + f]);
  }
}

// ---------------------------------------------------------------------------
// WT_l[n][k] = [w_l ; w_r]^T in bf16; L2 padded to 1024 rows (zero fill).
// Also zeroes the pooled output (re-poisoned to 0xAA before every launch).
__global__ __launch_bounds__(256) void k_cast_w(
    const float* __restrict__ w_l0, const float* __restrict__ w_r0,
    const float* __restrict__ w_l1, const float* __restrict__ w_r1,
    const float* __restrict__ w_l2, const float* __restrict__ w_r2,
    ushort_t* __restrict__ WT0, ushort_t* __restrict__ WT1,
    ushort_t* __restrict__ WT2, float* __restrict__ out) {
  int i = blockIdx.x * 256 + threadIdx.x;
  if (i < NIMG * NCLS) out[i] = 0.f;
  if (i < 98304) {                               // 256 x 384
    int n = i / 384, k = i - n * 384;
    float v = (k < 192) ? w_l0[k * 256 + n] : w_r0[(k - 192) * 256 + n];
    WT0[i] = f2bf_rne(v);
  } else if (i < 98304 + 131072) {               // 256 x 512
    int j = i - 98304;
    int n = j / 512, k = j - n * 512;
    float v = (k < 256) ? w_l1[k * 256 + n] : w_r1[(k - 256) * 256 + n];
    WT1[j] = f2bf_rne(v);
  } else {                                       // 1024 x 512 (rows>=1000: 0)
    int j = i - (98304 + 131072);
    int n = j / 512, k = j - n * 512;
    float v = 0.f;
    if (n < NCLS)
      v = (k < 256) ? w_l2[k * NCLS + n] : w_r2[(k - 256) * NCLS + n];
    WT2[j] = f2bf_rne(v);
  }
}

// ---------------------------------------------------------------------------
// layer-1/2 agg build, ushort4-vectorized: lane handles 4 consecutive cols.
// hsrc = Ab+256 (bf16, row stride 512); adst = Ab cols 0..255.
__global__ __launch_bounds__(256) void k_gather_h(
    const ushort_t* __restrict__ hsrc, const int* __restrict__ idx,
    ushort_t* __restrict__ adst) {
  int wid  = (blockIdx.x * 256 + threadIdx.x) >> 6;
  int lane = threadIdx.x & 63;
  if (wid >= NN) return;
  int nb[KNN];
#pragma unroll
  for (int n = 0; n < KNN; ++n) nb[n] = idx[wid * KNN + n];
  const int c0 = lane * 4;                   // 64 lanes x 4 cols = 256
  float s0 = 0.f, s1 = 0.f, s2 = 0.f, s3 = 0.f;
#pragma unroll
  for (int n = 0; n < KNN; ++n) {
    ushort4 v = *(const ushort4*)(hsrc + (size_t)nb[n] * 512 + c0);
    s0 += bf2f(v.x); s1 += bf2f(v.y); s2 += bf2f(v.z); s3 += bf2f(v.w);
  }
  ushort4 o;
  o.x = f2bf_rne(s0 * (1.0f / KNN));
  o.y = f2bf_rne(s1 * (1.0f / KNN));
  o.z = f2bf_rne(s2 * (1.0f / KNN));
  o.w = f2bf_rne(s3 * (1.0f / KNN));
  *(ushort4*)(adst + (size_t)wid * 512 + c0) = o;
}

// ---------------------------------------------------------------------------
// bf16 MFMA SAGE layer, BM=128 BN=64, N=256. hdst = next-layer Ab + 256.
__global__ __launch_bounds__(256, 4) void k_sage64(
    const ushort_t* __restrict__ Ab, const ushort_t* __restrict__ WT,
    const float* __restrict__ bias, ushort_t* __restrict__ hdst, int KT) {
  __shared__ __align__(16) char smem[12288];
  ushort_t* As = (ushort_t*)smem;            // [128][32]
  ushort_t* Bs = (ushort_t*)(smem + 8192);   // [64][32]

  const int t    = threadIdx.x;
  const int lane = t & 63;
  const int w    = t >> 6;
  const int l15  = lane & 15, lq = lane >> 4;
  const int rowStart = blockIdx.y * 128;
  const int colStart = blockIdx.x * 64;
  const int mrow = (w >> 1) * 64;
  const int ncol = (w & 1) * 32;

  const int rA0 = t >> 2, rA1 = rA0 + 64;
  const int g   = t & 3;
  const int gsA0 = g ^ (rA0 & 3), gsA1 = g ^ (rA1 & 3);
  const ushort_t* gA0 = Ab + (size_t)(rowStart + rA0) * KT + gsA0 * 8;
  const ushort_t* gA1 = Ab + (size_t)(rowStart + rA1) * KT + gsA1 * 8;
  const ushort_t* gB0 = WT + (size_t)(colStart + rA0) * KT + gsA0 * 8;
  ushort_t* lA0 = As + w * 512;
  ushort_t* lA1 = As + 2048 + w * 512;
  ushort_t* lB0 = Bs + w * 512;

  const int pg = (lq ^ (l15 & 3)) * 8;
  int aoff[4], boff[2];
#pragma unroll
  for (int ti = 0; ti < 4; ++ti) aoff[ti] = (mrow + ti * 16 + l15) * 32 + pg;
#pragma unroll
  for (int tj = 0; tj < 2; ++tj) boff[tj] = (ncol + tj * 16 + l15) * 32 + pg;

  f32x4 c00 = {}, c01 = {};
  f32x4 c10 = {}, c11 = {};
  f32x4 c20 = {}, c21 = {};
  f32x4 c30 = {}, c31 = {};

  const int nkt = KT >> 5;
#pragma unroll 1
  for (int kt = 0; kt < nkt; ++kt) {
    const int k0 = kt * 32;
    ASYNC16(gA0 + k0, lA0);
    ASYNC16(gA1 + k0, lA1);
    ASYNC16(gB0 + k0, lB0);
    __syncthreads();
    bf16x8 a0 = *(const bf16x8*)(As + aoff[0]);
    bf16x8 a1 = *(const bf16x8*)(As + aoff[1]);
    bf16x8 a2 = *(const bf16x8*)(As + aoff[2]);
    bf16x8 a3 = *(const bf16x8*)(As + aoff[3]);
    bf16x8 b0 = *(const bf16x8*)(Bs + boff[0]);
    bf16x8 b1 = *(const bf16x8*)(Bs + boff[1]);
    c00 = __builtin_amdgcn_mfma_f32_16x16x32_bf16(a0, b0, c00, 0, 0, 0);
    c01 = __builtin_amdgcn_mfma_f32_16x16x32_bf16(a0, b1, c01, 0, 0, 0);
    c10 = __builtin_amdgcn_mfma_f32_16x16x32_bf16(a1, b0, c10, 0, 0, 0);
    c11 = __builtin_amdgcn_mfma_f32_16x16x32_bf16(a1, b1, c11, 0, 0, 0);
    c20 = __builtin_amdgcn_mfma_f32_16x16x32_bf16(a2, b0, c20, 0, 0, 0);
    c21 = __builtin_amdgcn_mfma_f32_16x16x32_bf16(a2, b1, c21, 0, 0, 0);
    c30 = __builtin_amdgcn_mfma_f32_16x16x32_bf16(a3, b0, c30, 0, 0, 0);
    c31 = __builtin_amdgcn_mfma_f32_16x16x32_bf16(a3, b1, c31, 0, 0, 0);
    __syncthreads();
  }

  const float bv0 = bias[colStart + ncol + l15];
  const float bv1 = bias[colStart + ncol + 16 + l15];

#define S64_STORE(TI, TJ, CV, BV)                                            \
  do {                                                                       \
    f32x4 v_ = (CV);                                                         \
    int col_ = colStart + ncol + (TJ) * 16 + l15;                            \
    size_t rb_ = (size_t)(rowStart + mrow + (TI) * 16 + lq * 4);             \
    hdst[(rb_ + 0) * 512 + col_] = f2bf_rne(fmaxf(v_.x + (BV), 0.f));        \
    hdst[(rb_ + 1) * 512 + col_] = f2bf_rne(fmaxf(v_.y + (BV), 0.f));        \
    hdst[(rb_ + 2) * 512 + col_] = f2bf_rne(fmaxf(v_.z + (BV), 0.f));        \
    hdst[(rb_ + 3) * 512 + col_] = f2bf_rne(fmaxf(v_.w + (BV), 0.f));        \
  } while (0)

  S64_STORE(0, 0, c00, bv0); S64_STORE(0, 1, c01, bv1);
  S64_STORE(1, 0, c10, bv0); S64_STORE(1, 1, c11, bv1);
  S64_STORE(2, 0, c20, bv0); S64_STORE(2, 1, c21, bv1);
  S64_STORE(3, 0, c30, bv0); S64_STORE(3, 1, c31, bv1);
}

// ---------------------------------------------------------------------------
// bf16 MFMA layer-2 + fused global mean pool. BM=128 BN=128, N=1024 padded.
__global__ __launch_bounds__(256, 2) void k_sage128_pool(
    const ushort_t* __restrict__ Ab, const ushort_t* __restrict__ WT,
    const float* __restrict__ bias, float* __restrict__ out) {
  __shared__ __align__(16) char smem[16384];
  ushort_t* As = (ushort_t*)smem;            // [128][32]
  ushort_t* Bs = (ushort_t*)(smem + 8192);   // [128][32]
  __shared__ float Ps[2][128];

  const int t    = threadIdx.x;
  const int lane = t & 63;
  const int w    = t >> 6;
  const int l15  = lane & 15, lq = lane >> 4;
  const int rowStart = blockIdx.y * 128;
  const int colStart = blockIdx.x * 128;
  const int mrow = (w >> 1) * 64;
  const int ncol = (w & 1) * 64;
  const int KT = 512;

  const int rA0 = t >> 2, rA1 = rA0 + 64;
  const int g   = t & 3;
  const int gsA0 = g ^ (rA0 & 3), gsA1 = g ^ (rA1 & 3);
  const ushort_t* gA0 = Ab + (size_t)(rowStart + rA0) * KT + gsA0 * 8;
  const ushort_t* gA1 = Ab + (size_t)(rowStart + rA1) * KT + gsA1 * 8;
  const ushort_t* gB0 = WT + (size_t)(colStart + rA0) * KT + gsA0 * 8;
  const ushort_t* gB1 = WT + (size_t)(colStart + rA1) * KT + gsA1 * 8;
  ushort_t* lA0 = As + w * 512;
  ushort_t* lA1 = As + 2048 + w * 512;
  ushort_t* lB0 = Bs + w * 512;
  ushort_t* lB1 = Bs + 2048 + w * 512;

  const int pg = (lq ^ (l15 & 3)) * 8;
  int aoff[4], boff[4];
#pragma unroll
  for (int ti = 0; ti < 4; ++ti) aoff[ti] = (mrow + ti * 16 + l15) * 32 + pg;
#pragma unroll
  for (int tj = 0; tj < 4; ++tj) boff[tj] = (ncol + tj * 16 + l15) * 32 + pg;

  f32x4 c00 = {}, c01 = {}, c02 = {}, c03 = {};
  f32x4 c10 = {}, c11 = {}, c12 = {}, c13 = {};
  f32x4 c20 = {}, c21 = {}, c22 = {}, c23 = {};
  f32x4 c30 = {}, c31 = {}, c32 = {}, c33 = {};

#pragma unroll 1
  for (int kt = 0; kt < 16; ++kt) {
    const int k0 = kt * 32;
    ASYNC16(gA0 + k0, lA0);
    ASYNC16(gA1 + k0, lA1);
    ASYNC16(gB0 + k0, lB0);
    ASYNC16(gB1 + k0, lB1);
    __syncthreads();
    bf16x8 a0 = *(const bf16x8*)(As + aoff[0]);
    bf16x8 a1 = *(const bf16x8*)(As + aoff[1]);
    bf16x8 a2 = *(const bf16x8*)(As + aoff[2]);
    bf16x8 a3 = *(const bf16x8*)(As + aoff[3]);
    bf16x8 b0 = *(const bf16x8*)(Bs + boff[0]);
    bf16x8 b1 = *(const bf16x8*)(Bs + boff[1]);
    bf16x8 b2 = *(const bf16x8*)(Bs + boff[2]);
    bf16x8 b3 = *(const bf16x8*)(Bs + boff[3]);
    c00 = __builtin_amdgcn_mfma_f32_16x16x32_bf16(a0, b0, c00, 0, 0, 0);
    c01 = __builtin_amdgcn_mfma_f32_16x16x32_bf16(a0, b1, c01, 0, 0, 0);
    c02 = __builtin_amdgcn_mfma_f32_16x16x32_bf16(a0, b2, c02, 0, 0, 0);
    c03 = __builtin_amdgcn_mfma_f32_16x16x32_bf16(a0, b3, c03, 0, 0, 0);
    c10 = __builtin_amdgcn_mfma_f32_16x16x32_bf16(a1, b0, c10, 0, 0, 0);
    c11 = __builtin_amdgcn_mfma_f32_16x16x32_bf16(a1, b1, c11, 0, 0, 0);
    c12 = __builtin_amdgcn_mfma_f32_16x16x32_bf16(a1, b2, c12, 0, 0, 0);
    c13 = __builtin_amdgcn_mfma_f32_16x16x32_bf16(a1, b3, c13, 0, 0, 0);
    c20 = __builtin_amdgcn_mfma_f32_16x16x32_bf16(a2, b0, c20, 0, 0, 0);
    c21 = __builtin_amdgcn_mfma_f32_16x16x32_bf16(a2, b1, c21, 0, 0, 0);
    c22 = __builtin_amdgcn_mfma_f32_16x16x32_bf16(a2, b2, c22, 0, 0, 0);
    c23 = __builtin_amdgcn_mfma_f32_16x16x32_bf16(a2, b3, c23, 0, 0, 0);
    c30 = __builtin_amdgcn_mfma_f32_16x16x32_bf16(a3, b0, c30, 0, 0, 0);
    c31 = __builtin_amdgcn_mfma_f32_16x16x32_bf16(a3, b1, c31, 0, 0, 0);
    c32 = __builtin_amdgcn_mfma_f32_16x16x32_bf16(a3, b2, c32, 0, 0, 0);
    c33 = __builtin_amdgcn_mfma_f32_16x16x32_bf16(a3, b3, c33, 0, 0, 0);
    __syncthreads();
  }

#define P_ACC(CV)                                                            \
  (fmaxf((CV).x + bv_, 0.f) + fmaxf((CV).y + bv_, 0.f) +                     \
   fmaxf((CV).z + bv_, 0.f) + fmaxf((CV).w + bv_, 0.f))

#define POOL_COL(TJ, C0, C1, C2, C3)                                         \
  do {                                                                       \
    int col_ = colStart + ncol + (TJ) * 16 + l15;                            \
    float bv_ = (col_ < NCLS) ? bias[col_] : 0.f;                            \
    float s_ = P_ACC(C0) + P_ACC(C1) + P_ACC(C2) + P_ACC(C3);                \
    s_ += __shfl_xor(s_, 16);                                                \
    s_ += __shfl_xor(s_, 32);                                                \
    if (lq == 0) Ps[w >> 1][ncol + (TJ) * 16 + l15] = s_;                    \
  } while (0)

  POOL_COL(0, c00, c10, c20, c30);
  POOL_COL(1, c01, c11, c21, c31);
  POOL_COL(2, c02, c12, c22, c32);
  POOL_COL(3, c03, c13, c23, c33);

  __syncthreads();
  if (t < 128) {
    int col = colStart + t;
    if (col < NCLS) {
      float s = Ps[0][t] + Ps[1][t];
      int img = rowStart / NPP;
      atomicAdd(out + (size_t)img * NCLS + col, s * (1.0f / NPP));
    }
  }
}

// ---------------------------------------------------------------------------
extern "C" void kernel_launch(void* const* d_in, const int* in_sizes, int n_in,
                              void* d_out, int out_size, void* d_ws,
                              size_t ws_size, hipStream_t stream) {
  const float* x    = (const float*)d_in[0];
  const float* w_l0 = (const float*)d_in[1];
  const float* b_l0 = (const float*)d_in[2];
  const float* w_r0 = (const float*)d_in[3];
  const float* w_l1 = (const float*)d_in[4];
  const float* b_l1 = (const float*)d_in[5];
  const float* w_r1 = (const float*)d_in[6];
  const float* w_l2 = (const float*)d_in[7];
  const float* b_l2 = (const float*)d_in[8];
  const float* w_r2 = (const float*)d_in[9];
  float* out = (float*)d_out;

  char* ws = (char*)d_ws;
  // phase-1: sq 32KB | idx 288KB | cand(u32) 18.9MB | xs 6MB
  // phase-2 (overlaps dead cand region, written after k_reduce_gather):
  //   WT0 384KB | WT1 256KB | WT2 1MB | Ab0 6MB | Ab1 8MB | Ab2 8MB
  float*    sq   = (float*)(ws);
  int*      idx  = (int*)(ws + 32768);
  uint_t*   cand = (uint_t*)(ws + 327680);
  ushort_t* xs   = (ushort_t*)(ws + 28639232);
  ushort_t* WT0  = (ushort_t*)(ws + 327680);
  ushort_t* WT1  = (ushort_t*)(ws + 720896);
  ushort_t* WT2  = (ushort_t*)(ws + 983040);
  ushort_t* Ab0  = (ushort_t*)(ws + 2031616);
  ushort_t* Ab1  = (ushort_t*)(ws + 8323072);
  ushort_t* Ab2  = (ushort_t*)(ws + 16711680);

  // ---- kNN graph
  k_norms_split<<<2048, 256, 0, stream>>>(x, sq, xs);
  k_dist_topk<<<dim3(64, 64), 256, 0, stream>>>(xs, sq, cand);
  // NOTE: Ab0 overlaps the cand region? No — Ab0 at 2031616..8323071, cand
  // at 327680..19202047 DO overlap; k_reduce_gather reads cand[row] segment
  // (row*2304B) while writing Ab0[row] (768B at 2031616+row*768) — different
  // rows' regions interleave. Safe because every cand read for row r happens
  // before any Ab0 write for row r in the same wave, and Ab0[r] bytes
  // [2031616+768r, +768) map into cand rows < r only when 2031616+768r <
  // 327680+2304r' ... we order by processing rows in ascending wid with
  // gather writes landing at LOWER addresses than the cand rows still to be
  // read: 2031616+768*8191 = 8.3MB < 327680+2304*3500 — overlap with rows
  // ~1200..3500 which other waves may not have read yet. NOT safe in general
  // -> use the xs region (dead after dist) for Ab0 instead.
  k_reduce_gather<<<2048, 256, 0, stream>>>(cand, x, idx, xs /*as Ab0*/);
  k_cast_w<<<2944, 256, 0, stream>>>(w_l0, w_r0, w_l1, w_r1, w_l2, w_r2,
                                     WT0, WT1, WT2, out);
  // ---- layers (bf16 MFMA); Ab0 == xs (6 MB, row stride 384, exact reuse)
  k_sage64<<<dim3(4, 64), 256, 0, stream>>>(xs, WT0, b_l0, Ab1 + 256, 384);
  k_gather_h<<<2048, 256, 0, stream>>>(Ab1 + 256, idx, Ab1);
  k_sage64<<<dim3(4, 64), 256, 0, stream>>>(Ab1, WT1, b_l1, Ab2 + 256, 512);
  k_gather_h<<<2048, 256, 0, stream>>>(Ab2 + 256, idx, Ab2);
  k_sage128_pool<<<dim3(8, 64), 256, 0, stream>>>(Ab2, WT2, b_l2, out);
}

// Round 7
// 198.792 us; speedup vs baseline: 7.1680x; 1.1275x over previous
//
#include <hip/hip_runtime.h>

#define NN   8192
#define FEAT 192
#define HID  256
#define NCLS 1000
#define KNN  9
#define NPP  512          // nodes per image (8192 / 16)
#define NIMG 16
#define KD   192          // dist K (plain bf16 — see R7 note: split-bf16 was
                          // missing cross terms, so it was bf16-accurate anyway)
#define KL0  384          // layer-0 K ([agg|x])

typedef unsigned short ushort_t;
typedef unsigned int uint_t;
typedef __attribute__((ext_vector_type(8))) __bf16 bf16x8;
typedef __attribute__((ext_vector_type(4))) float f32x4;

#define ASYNC16(gptr, lptr)                                                  \
  __builtin_amdgcn_global_load_lds(                                          \
      (const __attribute__((address_space(1))) void*)(gptr),                 \
      (__attribute__((address_space(3))) void*)(lptr), 16, 0, 0)

// ---------------------------------------------------------------------------
__device__ __forceinline__ ushort_t f2bf_rne(float f) {
  unsigned u = __float_as_uint(f);
  u += 0x7FFF + ((u >> 16) & 1);          // round-to-nearest-even
  return (ushort_t)(u >> 16);
}
__device__ __forceinline__ float bf2f(ushort_t u) {
  return __uint_as_float((unsigned)u << 16);
}

// sortable-uint transform of float dist, top 19 bits kept, col13 in low bits.
__device__ __forceinline__ uint_t packkey(float f, int col) {
  uint_t b = __float_as_uint(f);
  uint_t m = (uint_t)((int)b >> 31) | 0x80000000u;
  uint_t u = b ^ m;
  return (u & 0xFFFFE000u) | (uint_t)col;
}

// branchless keep-9-smallest: one bubble pass through ascending-sorted tk[].
__device__ __forceinline__ void bubble9(uint_t (&tk)[KNN], uint_t k) {
#pragma unroll
  for (int p = 0; p < KNN; ++p) {
    uint_t lo = min(tk[p], k);
    k = max(tk[p], k);
    tk[p] = lo;
  }
}

// ---------------------------------------------------------------------------
// fused: row norms (fp32, exact) + bf16 cast (one pass over x). wave per row.
__global__ __launch_bounds__(256) void k_norms_split(
    const float* __restrict__ x, float* __restrict__ sq,
    ushort_t* __restrict__ xs) {
  int wid  = (blockIdx.x * 256 + threadIdx.x) >> 6;
  int lane = threadIdx.x & 63;
  if (wid >= NN) return;
  const float* row = x + (size_t)wid * FEAT;
  ushort_t* xr = xs + (size_t)wid * KD;
  float s = 0.f;
#pragma unroll
  for (int f0 = 0; f0 < FEAT; f0 += 64) {
    int f = f0 + lane;
    float v = row[f];
    s += v * v;
    xr[f] = f2bf_rne(v);
  }
#pragma unroll
  for (int off = 32; off > 0; off >>= 1) s += __shfl_down(s, off);
  if (lane == 0) sq[wid] = s;
}

// ---------------------------------------------------------------------------
// MFMA distance + per-colblock top-9, packed-u32 selection. K=192 bf16,
// 6 K-iterations. Staging/epilogue geometry identical to R6 (stride KD).
__global__ __launch_bounds__(256, 4) void k_dist_topk(
    const ushort_t* __restrict__ xs, const float* __restrict__ sq,
    uint_t* __restrict__ cand) {
  __shared__ __align__(16) char smem[24576];
  ushort_t* As = (ushort_t*)smem;            // [128][32] (granule-swizzled)
  ushort_t* Bs = (ushort_t*)(smem + 8192);
  uint_t*   Ms = (uint_t*)(smem + 19456);    // [128][10] merge buf

  const int t    = threadIdx.x;
  const int lane = t & 63;
  const int w    = t >> 6;
  const int l15  = lane & 15, lq = lane >> 4;
  const int rowStart = blockIdx.y * 128;
  const int colStart = blockIdx.x * 128;
  const int mrow = (w >> 1) * 64;            // wave's row quadrant
  const int ncol = (w & 1) * 64;             // wave's col quadrant

  const int m0 = w * 128 + lane;             // q=0 chunk; q=1 is m0+64
  const int r0 = m0 >> 2, r1 = r0 + 16;
  const int g0 = m0 & 3;
  const int gs0 = g0 ^ (r0 & 3);
  const int gs1 = g0 ^ (r1 & 3);
  const ushort_t* gA0 = xs + (size_t)(rowStart + r0) * KD + gs0 * 8;
  const ushort_t* gA1 = xs + (size_t)(rowStart + r1) * KD + gs1 * 8;
  const ushort_t* gB0 = xs + (size_t)(colStart + r0) * KD + gs0 * 8;
  const ushort_t* gB1 = xs + (size_t)(colStart + r1) * KD + gs1 * 8;
  ushort_t* lA = As + w * 1024;              // + q*512 elements
  ushort_t* lB = Bs + w * 1024;

  const int pg = (lq ^ (l15 & 3)) * 8;
  int aoff[4], boff[4];
#pragma unroll
  for (int ti = 0; ti < 4; ++ti) aoff[ti] = (mrow + ti * 16 + l15) * 32 + pg;
#pragma unroll
  for (int tj = 0; tj < 4; ++tj) boff[tj] = (ncol + tj * 16 + l15) * 32 + pg;

  f32x4 c00 = {}, c01 = {}, c02 = {}, c03 = {};
  f32x4 c10 = {}, c11 = {}, c12 = {}, c13 = {};
  f32x4 c20 = {}, c21 = {}, c22 = {}, c23 = {};
  f32x4 c30 = {}, c31 = {}, c32 = {}, c33 = {};

#pragma unroll 1
  for (int kt = 0; kt < 6; ++kt) {
    const int k0 = kt * 32;
    ASYNC16(gA0 + k0, lA);
    ASYNC16(gA1 + k0, lA + 512);
    ASYNC16(gB0 + k0, lB);
    ASYNC16(gB1 + k0, lB + 512);
    __syncthreads();
    bf16x8 a0 = *(const bf16x8*)(As + aoff[0]);
    bf16x8 a1 = *(const bf16x8*)(As + aoff[1]);
    bf16x8 a2 = *(const bf16x8*)(As + aoff[2]);
    bf16x8 a3 = *(const bf16x8*)(As + aoff[3]);
    bf16x8 b0 = *(const bf16x8*)(Bs + boff[0]);
    bf16x8 b1 = *(const bf16x8*)(Bs + boff[1]);
    bf16x8 b2 = *(const bf16x8*)(Bs + boff[2]);
    bf16x8 b3 = *(const bf16x8*)(Bs + boff[3]);
    c00 = __builtin_amdgcn_mfma_f32_16x16x32_bf16(a0, b0, c00, 0, 0, 0);
    c01 = __builtin_amdgcn_mfma_f32_16x16x32_bf16(a0, b1, c01, 0, 0, 0);
    c02 = __builtin_amdgcn_mfma_f32_16x16x32_bf16(a0, b2, c02, 0, 0, 0);
    c03 = __builtin_amdgcn_mfma_f32_16x16x32_bf16(a0, b3, c03, 0, 0, 0);
    c10 = __builtin_amdgcn_mfma_f32_16x16x32_bf16(a1, b0, c10, 0, 0, 0);
    c11 = __builtin_amdgcn_mfma_f32_16x16x32_bf16(a1, b1, c11, 0, 0, 0);
    c12 = __builtin_amdgcn_mfma_f32_16x16x32_bf16(a1, b2, c12, 0, 0, 0);
    c13 = __builtin_amdgcn_mfma_f32_16x16x32_bf16(a1, b3, c13, 0, 0, 0);
    c20 = __builtin_amdgcn_mfma_f32_16x16x32_bf16(a2, b0, c20, 0, 0, 0);
    c21 = __builtin_amdgcn_mfma_f32_16x16x32_bf16(a2, b1, c21, 0, 0, 0);
    c22 = __builtin_amdgcn_mfma_f32_16x16x32_bf16(a2, b2, c22, 0, 0, 0);
    c23 = __builtin_amdgcn_mfma_f32_16x16x32_bf16(a2, b3, c23, 0, 0, 0);
    c30 = __builtin_amdgcn_mfma_f32_16x16x32_bf16(a3, b0, c30, 0, 0, 0);
    c31 = __builtin_amdgcn_mfma_f32_16x16x32_bf16(a3, b1, c31, 0, 0, 0);
    c32 = __builtin_amdgcn_mfma_f32_16x16x32_bf16(a3, b2, c32, 0, 0, 0);
    c33 = __builtin_amdgcn_mfma_f32_16x16x32_bf16(a3, b3, c33, 0, 0, 0);
    __syncthreads();                         // all waves past K-loop
  }

  // ---- epilogue: key = pack(sq[j] - 2*dot, col); per-row top-9 (packed)
  uint_t tk[KNN];
#pragma unroll
  for (int n = 0; n < KNN; ++n) tk[n] = 0xFFFFFFFFu;

  uint_t* Ew = (uint_t*)smem + w * (64 * 19);   // per-wave private scratch

#define EPI_ROW(TI, CV)                                                      \
  do {                                                                       \
    f32x4 v_ = (CV);                                                         \
    Ew[((TI) * 16 + lq * 4 + 0) * 19 + l15] =                                \
        packkey(fmaf(-2.0f, v_.x, sqv), mycol);                              \
    Ew[((TI) * 16 + lq * 4 + 1) * 19 + l15] =                                \
        packkey(fmaf(-2.0f, v_.y, sqv), mycol);                              \
    Ew[((TI) * 16 + lq * 4 + 2) * 19 + l15] =                                \
        packkey(fmaf(-2.0f, v_.z, sqv), mycol);                              \
    Ew[((TI) * 16 + lq * 4 + 3) * 19 + l15] =                                \
        packkey(fmaf(-2.0f, v_.w, sqv), mycol);                              \
  } while (0)

#define EPI_TILE(TJ, C0, C1, C2, C3)                                         \
  do {                                                                       \
    int mycol = colStart + ncol + (TJ) * 16 + l15;                           \
    float sqv = sq[mycol];                                                   \
    EPI_ROW(0, C0); EPI_ROW(1, C1); EPI_ROW(2, C2); EPI_ROW(3, C3);          \
    _Pragma("unroll")                                                        \
    for (int c = 0; c < 16; ++c) bubble9(tk, Ew[lane * 19 + c]);             \
  } while (0)

  EPI_TILE(0, c00, c10, c20, c30);
  EPI_TILE(1, c01, c11, c21, c31);
  EPI_TILE(2, c02, c12, c22, c32);
  EPI_TILE(3, c03, c13, c23, c33);

  // merge the two waves sharing each row half, write candidates
  __syncthreads();
  if (w & 1) {
#pragma unroll
    for (int n = 0; n < KNN; ++n) Ms[(mrow + lane) * 10 + n] = tk[n];
  }
  __syncthreads();
  if (!(w & 1)) {
#pragma unroll
    for (int n = 0; n < KNN; ++n) bubble9(tk, Ms[(mrow + lane) * 10 + n]);
    size_t base = (((size_t)(rowStart + mrow + lane)) * 64 + blockIdx.x) * KNN;
#pragma unroll
    for (int n = 0; n < KNN; ++n) cand[base + n] = tk[n];
  }
}

// ---------------------------------------------------------------------------
// fused: merge 64x9 packed candidates -> 9 neighbor idx -> layer-0 gather.
__global__ __launch_bounds__(256) void k_reduce_gather(
    const uint_t* __restrict__ cand, const float* __restrict__ x,
    int* __restrict__ idx, ushort_t* __restrict__ Ab0) {
  int wid  = (blockIdx.x * 256 + threadIdx.x) >> 6;
  int lane = threadIdx.x & 63;
  if (wid >= NN) return;
  const uint_t* cv = cand + (size_t)wid * 576;
  uint_t tk[KNN];
#pragma unroll
  for (int n = 0; n < KNN; ++n) tk[n] = 0xFFFFFFFFu;
#pragma unroll
  for (int m = 0; m < KNN; ++m) bubble9(tk, cv[lane + 64 * m]);

  int nb[KNN];
  for (int r = 0; r < KNN; ++r) {
    uint_t bm = tk[0];                       // lane-local min (sorted)
#pragma unroll
    for (int off = 32; off > 0; off >>= 1)
      bm = min(bm, (uint_t)__shfl_xor((unsigned int)bm, off));
    if (tk[0] == bm) {                       // keys unique: exactly one lane
#pragma unroll
      for (int p = 0; p < KNN - 1; ++p) tk[p] = tk[p + 1];
      tk[KNN - 1] = 0xFFFFFFFFu;
    }
    nb[r] = (int)(bm & 0x1FFFu);             // all lanes keep the winner
    if (lane == 0) idx[wid * KNN + r] = nb[r];
  }

  // layer-0 input build: Ab0[row][0..191]=bf16(mean9 x), [192..383]=bf16(x)
#pragma unroll
  for (int f0 = 0; f0 < FEAT; f0 += 64) {
    int f = f0 + lane;
    float s = 0.f;
#pragma unroll
    for (int n = 0; n < KNN; ++n) s += x[(size_t)nb[n] * FEAT + f];
    Ab0[(size_t)wid * KL0 + f]        = f2bf_rne(s * (1.0f / KNN));
    Ab0[(size_t)wid * KL0 + FEAT + f] = f2bf_rne(x[(size_t)wid * FEAT + f]);
  }
}

// ---------------------------------------------------------------------------
// WT_l[n][k] = [w_l ; w_r]^T in bf16; L2 padded to 1024 rows (zero fill).
// Also zeroes the pooled output (re-poisoned to 0xAA before every launch).
__global__ __launch_bounds__(256) void k_cast_w(
    const float* __restrict__ w_l0, const float* __restrict__ w_r0,
    const float* __restrict__ w_l1, const float* __restrict__ w_r1,
    const float* __restrict__ w_l2, const float* __restrict__ w_r2,
    ushort_t* __restrict__ WT0, ushort_t* __restrict__ WT1,
    ushort_t* __restrict__ WT2, float* __restrict__ out) {
  int i = blockIdx.x * 256 + threadIdx.x;
  if (i < NIMG * NCLS) out[i] = 0.f;
  if (i < 98304) {                               // 256 x 384
    int n = i / 384, k = i - n * 384;
    float v = (k < 192) ? w_l0[k * 256 + n] : w_r0[(k - 192) * 256 + n];
    WT0[i] = f2bf_rne(v);
  } else if (i < 98304 + 131072) {               // 256 x 512
    int j = i - 98304;
    int n = j / 512, k = j - n * 512;
    float v = (k < 256) ? w_l1[k * 256 + n] : w_r1[(k - 256) * 256 + n];
    WT1[j] = f2bf_rne(v);
  } else {                                       // 1024 x 512 (rows>=1000: 0)
    int j = i - (98304 + 131072);
    int n = j / 512, k = j - n * 512;
    float v = 0.f;
    if (n < NCLS)
      v = (k < 256) ? w_l2[k * NCLS + n] : w_r2[(k - 256) * NCLS + n];
    WT2[j] = f2bf_rne(v);
  }
}

// ---------------------------------------------------------------------------
// layer-1/2 agg build, ushort4-vectorized: lane handles 4 consecutive cols.
__global__ __launch_bounds__(256) void k_gather_h(
    const ushort_t* __restrict__ hsrc, const int* __restrict__ idx,
    ushort_t* __restrict__ adst) {
  int wid  = (blockIdx.x * 256 + threadIdx.x) >> 6;
  int lane = threadIdx.x & 63;
  if (wid >= NN) return;
  int nb[KNN];
#pragma unroll
  for (int n = 0; n < KNN; ++n) nb[n] = idx[wid * KNN + n];
  const int c0 = lane * 4;                   // 64 lanes x 4 cols = 256
  float s0 = 0.f, s1 = 0.f, s2 = 0.f, s3 = 0.f;
#pragma unroll
  for (int n = 0; n < KNN; ++n) {
    ushort4 v = *(const ushort4*)(hsrc + (size_t)nb[n] * 512 + c0);
    s0 += bf2f(v.x); s1 += bf2f(v.y); s2 += bf2f(v.z); s3 += bf2f(v.w);
  }
  ushort4 o;
  o.x = f2bf_rne(s0 * (1.0f / KNN));
  o.y = f2bf_rne(s1 * (1.0f / KNN));
  o.z = f2bf_rne(s2 * (1.0f / KNN));
  o.w = f2bf_rne(s3 * (1.0f / KNN));
  *(ushort4*)(adst + (size_t)wid * 512 + c0) = o;
}

// ---------------------------------------------------------------------------
// bf16 MFMA SAGE layer, BM=128 BN=64, N=256. hdst = next-layer Ab + 256.
__global__ __launch_bounds__(256, 4) void k_sage64(
    const ushort_t* __restrict__ Ab, const ushort_t* __restrict__ WT,
    const float* __restrict__ bias, ushort_t* __restrict__ hdst, int KT) {
  __shared__ __align__(16) char smem[12288];
  ushort_t* As = (ushort_t*)smem;            // [128][32]
  ushort_t* Bs = (ushort_t*)(smem + 8192);   // [64][32]

  const int t    = threadIdx.x;
  const int lane = t & 63;
  const int w    = t >> 6;
  const int l15  = lane & 15, lq = lane >> 4;
  const int rowStart = blockIdx.y * 128;
  const int colStart = blockIdx.x * 64;
  const int mrow = (w >> 1) * 64;
  const int ncol = (w & 1) * 32;

  const int rA0 = t >> 2, rA1 = rA0 + 64;
  const int g   = t & 3;
  const int gsA0 = g ^ (rA0 & 3), gsA1 = g ^ (rA1 & 3);
  const ushort_t* gA0 = Ab + (size_t)(rowStart + rA0) * KT + gsA0 * 8;
  const ushort_t* gA1 = Ab + (size_t)(rowStart + rA1) * KT + gsA1 * 8;
  const ushort_t* gB0 = WT + (size_t)(colStart + rA0) * KT + gsA0 * 8;
  ushort_t* lA0 = As + w * 512;
  ushort_t* lA1 = As + 2048 + w * 512;
  ushort_t* lB0 = Bs + w * 512;

  const int pg = (lq ^ (l15 & 3)) * 8;
  int aoff[4], boff[2];
#pragma unroll
  for (int ti = 0; ti < 4; ++ti) aoff[ti] = (mrow + ti * 16 + l15) * 32 + pg;
#pragma unroll
  for (int tj = 0; tj < 2; ++tj) boff[tj] = (ncol + tj * 16 + l15) * 32 + pg;

  f32x4 c00 = {}, c01 = {};
  f32x4 c10 = {}, c11 = {};
  f32x4 c20 = {}, c21 = {};
  f32x4 c30 = {}, c31 = {};

  const int nkt = KT >> 5;
#pragma unroll 1
  for (int kt = 0; kt < nkt; ++kt) {
    const int k0 = kt * 32;
    ASYNC16(gA0 + k0, lA0);
    ASYNC16(gA1 + k0, lA1);
    ASYNC16(gB0 + k0, lB0);
    __syncthreads();
    bf16x8 a0 = *(const bf16x8*)(As + aoff[0]);
    bf16x8 a1 = *(const bf16x8*)(As + aoff[1]);
    bf16x8 a2 = *(const bf16x8*)(As + aoff[2]);
    bf16x8 a3 = *(const bf16x8*)(As + aoff[3]);
    bf16x8 b0 = *(const bf16x8*)(Bs + boff[0]);
    bf16x8 b1 = *(const bf16x8*)(Bs + boff[1]);
    c00 = __builtin_amdgcn_mfma_f32_16x16x32_bf16(a0, b0, c00, 0, 0, 0);
    c01 = __builtin_amdgcn_mfma_f32_16x16x32_bf16(a0, b1, c01, 0, 0, 0);
    c10 = __builtin_amdgcn_mfma_f32_16x16x32_bf16(a1, b0, c10, 0, 0, 0);
    c11 = __builtin_amdgcn_mfma_f32_16x16x32_bf16(a1, b1, c11, 0, 0, 0);
    c20 = __builtin_amdgcn_mfma_f32_16x16x32_bf16(a2, b0, c20, 0, 0, 0);
    c21 = __builtin_amdgcn_mfma_f32_16x16x32_bf16(a2, b1, c21, 0, 0, 0);
    c30 = __builtin_amdgcn_mfma_f32_16x16x32_bf16(a3, b0, c30, 0, 0, 0);
    c31 = __builtin_amdgcn_mfma_f32_16x16x32_bf16(a3, b1, c31, 0, 0, 0);
    __syncthreads();
  }

  const float bv0 = bias[colStart + ncol + l15];
  const float bv1 = bias[colStart + ncol + 16 + l15];

#define S64_STORE(TI, TJ, CV, BV)                                            \
  do {                                                                       \
    f32x4 v_ = (CV);                                                         \
    int col_ = colStart + ncol + (TJ) * 16 + l15;                            \
    size_t rb_ = (size_t)(rowStart + mrow + (TI) * 16 + lq * 4);             \
    hdst[(rb_ + 0) * 512 + col_] = f2bf_rne(fmaxf(v_.x + (BV), 0.f));        \
    hdst[(rb_ + 1) * 512 + col_] = f2bf_rne(fmaxf(v_.y + (BV), 0.f));        \
    hdst[(rb_ + 2) * 512 + col_] = f2bf_rne(fmaxf(v_.z + (BV), 0.f));        \
    hdst[(rb_ + 3) * 512 + col_] = f2bf_rne(fmaxf(v_.w + (BV), 0.f));        \
  } while (0)

  S64_STORE(0, 0, c00, bv0); S64_STORE(0, 1, c01, bv1);
  S64_STORE(1, 0, c10, bv0); S64_STORE(1, 1, c11, bv1);
  S64_STORE(2, 0, c20, bv0); S64_STORE(2, 1, c21, bv1);
  S64_STORE(3, 0, c30, bv0); S64_STORE(3, 1, c31, bv1);
}

// ---------------------------------------------------------------------------
// bf16 MFMA layer-2 + fused global mean pool. BM=128 BN=128, N=1024 padded.
__global__ __launch_bounds__(256, 2) void k_sage128_pool(
    const ushort_t* __restrict__ Ab, const ushort_t* __restrict__ WT,
    const float* __restrict__ bias, float* __restrict__ out) {
  __shared__ __align__(16) char smem[16384];
  ushort_t* As = (ushort_t*)smem;            // [128][32]
  ushort_t* Bs = (ushort_t*)(smem + 8192);   // [128][32]
  __shared__ float Ps[2][128];

  const int t    = threadIdx.x;
  const int lane = t & 63;
  const int w    = t >> 6;
  const int l15  = lane & 15, lq = lane >> 4;
  const int rowStart = blockIdx.y * 128;
  const int colStart = blockIdx.x * 128;
  const int mrow = (w >> 1) * 64;
  const int ncol = (w & 1) * 64;
  const int KT = 512;

  const int rA0 = t >> 2, rA1 = rA0 + 64;
  const int g   = t & 3;
  const int gsA0 = g ^ (rA0 & 3), gsA1 = g ^ (rA1 & 3);
  const ushort_t* gA0 = Ab + (size_t)(rowStart + rA0) * KT + gsA0 * 8;
  const ushort_t* gA1 = Ab + (size_t)(rowStart + rA1) * KT + gsA1 * 8;
  const ushort_t* gB0 = WT + (size_t)(colStart + rA0) * KT + gsA0 * 8;
  const ushort_t* gB1 = WT + (size_t)(colStart + rA1) * KT + gsA1 * 8;
  ushort_t* lA0 = As + w * 512;
  ushort_t* lA1 = As + 2048 + w * 512;
  ushort_t* lB0 = Bs + w * 512;
  ushort_t* lB1 = Bs + 2048 + w * 512;

  const int pg = (lq ^ (l15 & 3)) * 8;
  int aoff[4], boff[4];
#pragma unroll
  for (int ti = 0; ti < 4; ++ti) aoff[ti] = (mrow + ti * 16 + l15) * 32 + pg;
#pragma unroll
  for (int tj = 0; tj < 4; ++tj) boff[tj] = (ncol + tj * 16 + l15) * 32 + pg;

  f32x4 c00 = {}, c01 = {}, c02 = {}, c03 = {};
  f32x4 c10 = {}, c11 = {}, c12 = {}, c13 = {};
  f32x4 c20 = {}, c21 = {}, c22 = {}, c23 = {};
  f32x4 c30 = {}, c31 = {}, c32 = {}, c33 = {};

#pragma unroll 1
  for (int kt = 0; kt < 16; ++kt) {
    const int k0 = kt * 32;
    ASYNC16(gA0 + k0, lA0);
    ASYNC16(gA1 + k0, lA1);
    ASYNC16(gB0 + k0, lB0);
    ASYNC16(gB1 + k0, lB1);
    __syncthreads();
    bf16x8 a0 = *(const bf16x8*)(As + aoff[0]);
    bf16x8 a1 = *(const bf16x8*)(As + aoff[1]);
    bf16x8 a2 = *(const bf16x8*)(As + aoff[2]);
    bf16x8 a3 = *(const bf16x8*)(As + aoff[3]);
    bf16x8 b0 = *(const bf16x8*)(Bs + boff[0]);
    bf16x8 b1 = *(const bf16x8*)(Bs + boff[1]);
    bf16x8 b2 = *(const bf16x8*)(Bs + boff[2]);
    bf16x8 b3 = *(const bf16x8*)(Bs + boff[3]);
    c00 = __builtin_amdgcn_mfma_f32_16x16x32_bf16(a0, b0, c00, 0, 0, 0);
    c01 = __builtin_amdgcn_mfma_f32_16x16x32_bf16(a0, b1, c01, 0, 0, 0);
    c02 = __builtin_amdgcn_mfma_f32_16x16x32_bf16(a0, b2, c02, 0, 0, 0);
    c03 = __builtin_amdgcn_mfma_f32_16x16x32_bf16(a0, b3, c03, 0, 0, 0);
    c10 = __builtin_amdgcn_mfma_f32_16x16x32_bf16(a1, b0, c10, 0, 0, 0);
    c11 = __builtin_amdgcn_mfma_f32_16x16x32_bf16(a1, b1, c11, 0, 0, 0);
    c12 = __builtin_amdgcn_mfma_f32_16x16x32_bf16(a1, b2, c12, 0, 0, 0);
    c13 = __builtin_amdgcn_mfma_f32_16x16x32_bf16(a1, b3, c13, 0, 0, 0);
    c20 = __builtin_amdgcn_mfma_f32_16x16x32_bf16(a2, b0, c20, 0, 0, 0);
    c21 = __builtin_amdgcn_mfma_f32_16x16x32_bf16(a2, b1, c21, 0, 0, 0);
    c22 = __builtin_amdgcn_mfma_f32_16x16x32_bf16(a2, b2, c22, 0, 0, 0);
    c23 = __builtin_amdgcn_mfma_f32_16x16x32_bf16(a2, b3, c23, 0, 0, 0);
    c30 = __builtin_amdgcn_mfma_f32_16x16x32_bf16(a3, b0, c30, 0, 0, 0);
    c31 = __builtin_amdgcn_mfma_f32_16x16x32_bf16(a3, b1, c31, 0, 0, 0);
    c32 = __builtin_amdgcn_mfma_f32_16x16x32_bf16(a3, b2, c32, 0, 0, 0);
    c33 = __builtin_amdgcn_mfma_f32_16x16x32_bf16(a3, b3, c33, 0, 0, 0);
    __syncthreads();
  }

#define P_ACC(CV)                                                            \
  (fmaxf((CV).x + bv_, 0.f) + fmaxf((CV).y + bv_, 0.f) +                     \
   fmaxf((CV).z + bv_, 0.f) + fmaxf((CV).w + bv_, 0.f))

#define POOL_COL(TJ, C0, C1, C2, C3)                                         \
  do {                                                                       \
    int col_ = colStart + ncol + (TJ) * 16 + l15;                            \
    float bv_ = (col_ < NCLS) ? bias[col_] : 0.f;                            \
    float s_ = P_ACC(C0) + P_ACC(C1) + P_ACC(C2) + P_ACC(C3);                \
    s_ += __shfl_xor(s_, 16);                                                \
    s_ += __shfl_xor(s_, 32);                                                \
    if (lq == 0) Ps[w >> 1][ncol + (TJ) * 16 + l15] = s_;                    \
  } while (0)

  POOL_COL(0, c00, c10, c20, c30);
  POOL_COL(1, c01, c11, c21, c31);
  POOL_COL(2, c02, c12, c22, c32);
  POOL_COL(3, c03, c13, c23, c33);

  __syncthreads();
  if (t < 128) {
    int col = colStart + t;
    if (col < NCLS) {
      float s = Ps[0][t] + Ps[1][t];
      int img = rowStart / NPP;
      atomicAdd(out + (size_t)img * NCLS + col, s * (1.0f / NPP));
    }
  }
}

// ---------------------------------------------------------------------------
extern "C" void kernel_launch(void* const* d_in, const int* in_sizes, int n_in,
                              void* d_out, int out_size, void* d_ws,
                              size_t ws_size, hipStream_t stream) {
  const float* x    = (const float*)d_in[0];
  const float* w_l0 = (const float*)d_in[1];
  const float* b_l0 = (const float*)d_in[2];
  const float* w_r0 = (const float*)d_in[3];
  const float* w_l1 = (const float*)d_in[4];
  const float* b_l1 = (const float*)d_in[5];
  const float* w_r1 = (const float*)d_in[6];
  const float* w_l2 = (const float*)d_in[7];
  const float* b_l2 = (const float*)d_in[8];
  const float* w_r2 = (const float*)d_in[9];
  float* out = (float*)d_out;

  char* ws = (char*)d_ws;
  // non-overlapping: sq 32K | idx 288K | cand 18.87M | xs(bf16,K=192) 3M |
  // Ab0 6.29M  (peak 28.64 MB).
  // WT0/WT1/WT2/Ab1/Ab2 live inside the cand region, which is dead after
  // k_reduce_gather; k_cast_w runs after it (stream-ordered).
  float*    sq   = (float*)(ws);
  int*      idx  = (int*)(ws + 32768);
  uint_t*   cand = (uint_t*)(ws + 327680);
  ushort_t* xs   = (ushort_t*)(ws + 19202048);
  ushort_t* Ab0  = (ushort_t*)(ws + 22347776);
  ushort_t* WT0  = (ushort_t*)(ws + 327680);
  ushort_t* WT1  = (ushort_t*)(ws + 524288);
  ushort_t* WT2  = (ushort_t*)(ws + 786432);
  ushort_t* Ab1  = (ushort_t*)(ws + 1835008);
  ushort_t* Ab2  = (ushort_t*)(ws + 10223616);

  // ---- kNN graph
  k_norms_split<<<2048, 256, 0, stream>>>(x, sq, xs);
  k_dist_topk<<<dim3(64, 64), 256, 0, stream>>>(xs, sq, cand);
  k_reduce_gather<<<2048, 256, 0, stream>>>(cand, x, idx, Ab0);
  k_cast_w<<<2944, 256, 0, stream>>>(w_l0, w_r0, w_l1, w_r1, w_l2, w_r2,
                                     WT0, WT1, WT2, out);
  // ---- layers (bf16 MFMA)
  k_sage64<<<dim3(4, 64), 256, 0, stream>>>(Ab0, WT0, b_l0, Ab1 + 256, KL0);
  k_gather_h<<<2048, 256, 0, stream>>>(Ab1 + 256, idx, Ab1);
  k_sage64<<<dim3(4, 64), 256, 0, stream>>>(Ab1, WT1, b_l1, Ab2 + 256, 512);
  k_gather_h<<<2048, 256, 0, stream>>>(Ab2 + 256, idx, Ab2);
  k_sage128_pool<<<dim3(8, 64), 256, 0, stream>>>(Ab2, WT2, b_l2, out);
}